// Round 12
// baseline (318.013 us; speedup 1.0000x reference)
//
#include <hip/hip_runtime.h>

// TemporalDilatedAttention on gfx950 — round 18
// vs R17 (PASSED 309.7us, best): PH/S MfmaUtil pinned at 27.7% == EXACTLY
// MFMA/(LDS+MFMA+bar) = 310/1120 cyc per tile — my phases read fragments
// for the CURRENT MFMA (serial). m201's actual mechanism: reads fetch the
// NEXT phase's fragments so they hide under the current MFMA. R18: 256^2
// core pipelines FRAGMENTS ACROSS TILES — at tile t issue ds_reads for
// B/A-lo(t+1) + A-hi(t), then MFMA tile t from regs loaded last iter.
// Compiler emits lgkmcnt(12)/(8) before the MFMA clusters -> reads overlap
// MFMA; ONE barrier/tile (was 3). Staging/vmcnt/4-buf ledger identical to
// R17; MFMA order per acc unchanged (bit-identical numerics). +80 VGPR for
// 20 half8 frag regs (~230 total < 256 cap @ launch_bounds(512,2)).

#define DD    1024
#define TALL  16384

typedef _Float16 half8  __attribute__((ext_vector_type(8)));
typedef _Float16 half4v __attribute__((ext_vector_type(4)));
typedef float    floatx4 __attribute__((ext_vector_type(4)));
typedef unsigned int u32;

// ---------------- workspace layout (bytes), ~132.5 MB ----------------
static const size_t OFF_WOT  = 0;          // 2 MB  Wo^T f16
static const size_t OFF_WV16 = 2097152;    // 2 MB  Wv f16
static const size_t OFF_WK16 = 4194304;    // 2 MB  Wk f16
static const size_t OFF_WQ16 = 6291456;    // 2 MB  Wq f16
static const size_t OFF_XB   = 8388608;    // 0.5 MB x f16
static const size_t OFF_G    = 8912896;    // 2 MB  G f16; w4 table after S
static const size_t OFF_WVOT = 11010048;   // 8 MB  WVOT f16 (LIVE through FO)
static const size_t OFF_WQKT = 19398656;   // 8 MB  WQKT f16 (dead after G); zframe after S
static const size_t OFF_BVWO = 27787264;   // 4 KB  bv@Wo f32
static const size_t OFF_BQK  = 27791360;   // 16 KB bqk f32
static const size_t OFF_PHR  = 27807744;   // 2 MB  PHred f16
static const size_t OFF_OPP  = 29904896;   // 8 MB  FO partials f32
static const size_t OFF_HB   = 38293504;   // 32 MB histb (dead after S)
static const size_t OFF_HT   = 71848960;   // 32 MB hist^T f16 [feat][t]
static const size_t OFF_S    = 105403392;  // 32 MB E = exp(S) f16 [h][q][t]

// PH f16 partial chunks: 16 x 2 MB over regions dead during launches 6-7.
__device__ __forceinline__ size_t chunk16_off(int g) {
  if (g < 4)  return (size_t)g * 2097152;
  if (g < 8)  return 19398656 + (size_t)(g - 4) * 2097152;
  if (g < 12) return 29904896 + (size_t)(g - 8) * 2097152;
  return 38293504 + (size_t)(g - 12) * 2097152;
}

// Frame-class chunk map: chunk g, sub-frame j (0..3) -> frame index.
// g<12: the 48 frames with f%4!=0 (f = m + m/3 + 1 enumerates them);
// g=12,13: f%4==0 && f%8!=0; g=14: f%8==0 && f%16!=0; g=15: f%16==0.
__device__ __forceinline__ int frame_of(int g, int j) {
  if (g < 12) { int m = g * 4 + j; return m + m / 3 + 1; }
  if (g < 14) return 4 + 8 * ((g - 12) * 4 + j);
  if (g == 14) return 8 + 16 * j;
  return 16 * j;
}
// Per-tile byte offset into a 16384-col f16 row for chunk g, tile t (0..31).
__device__ __forceinline__ size_t foff(int g, int t) {
  return (size_t)frame_of(g, t >> 3) * 512 + (size_t)(t & 7) * 64;
}

struct LinOff { __device__ __forceinline__ size_t operator()(int t) const { return (size_t)t * 64; } };
struct ClsOff { int g; __device__ __forceinline__ size_t operator()(int t) const { return foff(g, t); } };

// ---------------- async global->LDS, 16B per lane ----------------
__device__ __forceinline__ void gl_lds16(const void* g, void* l) {
  __builtin_amdgcn_global_load_lds((const __attribute__((address_space(1))) u32*)g,
                                   (__attribute__((address_space(3))) u32*)l, 16, 0, 0);
}

// ---------------- prep (unchanged) ----------------
__global__ void prep_kernel(const float* __restrict__ Wo, const float* __restrict__ Wv,
                            const float* __restrict__ Wk, const float* __restrict__ Wq,
                            const float* __restrict__ x, const float* __restrict__ hist,
                            _Float16* __restrict__ WoT, _Float16* __restrict__ Wv16,
                            _Float16* __restrict__ Wk16, _Float16* __restrict__ Wq16,
                            _Float16* __restrict__ xb, _Float16* __restrict__ histb,
                            _Float16* __restrict__ histT) {
  int bid = blockIdx.x, tid = threadIdx.x;
  if (bid < 1024) {                        // Wo transpose+cvt
    int k0 = (bid & 31) * 32, n0 = (bid >> 5) * 32;
    __shared__ float t32[32][33];
    int tx = tid & 31, ty = tid >> 5;
#pragma unroll
    for (int i = 0; i < 4; i++) {
      int r = ty + i * 8;
      t32[r][tx] = Wo[(size_t)(k0 + r) * DD + n0 + tx];
    }
    __syncthreads();
#pragma unroll
    for (int i = 0; i < 4; i++) {
      int r = ty + i * 8;
      WoT[(size_t)(n0 + r) * DD + k0 + tx] = (_Float16)t32[tx][r];
    }
  } else if (bid < 4352) {                 // plain cvt
    const float* src; _Float16* dst; size_t i;
    if (bid < 2048)      { src = Wv; dst = Wv16; i = (size_t)(bid - 1024) * 256 + tid; }
    else if (bid < 3072) { src = Wk; dst = Wk16; i = (size_t)(bid - 2048) * 256 + tid; }
    else if (bid < 4096) { src = Wq; dst = Wq16; i = (size_t)(bid - 3072) * 256 + tid; }
    else                 { src = x;  dst = xb;   i = (size_t)(bid - 4096) * 256 + tid; }
    float4 v = ((const float4*)src)[i];
    half4v h = {(_Float16)v.x, (_Float16)v.y, (_Float16)v.z, (_Float16)v.w};
    *(half4v*)(dst + 4 * i) = h;
  } else {                                 // hist dual write
    int tb = bid - 4352;
    int t0 = (tb & 255) * 64, f0 = (tb >> 8) * 64;
    __shared__ _Float16 lt[64][72];
    int r = tid >> 2, c0 = (tid & 3) * 16;
    half8 s0, s1;
#pragma unroll
    for (int i = 0; i < 4; i++) {
      float4 v = *(const float4*)&hist[(size_t)(t0 + r) * 1024 + f0 + c0 + i * 4];
      half4v h = {(_Float16)v.x, (_Float16)v.y, (_Float16)v.z, (_Float16)v.w};
      *(half4v*)&lt[r][c0 + i * 4] = h;
      if (i < 2) { s0[i*4]=h[0]; s0[i*4+1]=h[1]; s0[i*4+2]=h[2]; s0[i*4+3]=h[3]; }
      else { s1[(i-2)*4]=h[0]; s1[(i-2)*4+1]=h[1]; s1[(i-2)*4+2]=h[2]; s1[(i-2)*4+3]=h[3]; }
    }
    *(half8*)&histb[(size_t)(t0 + r) * 1024 + f0 + c0] = s0;
    *(half8*)&histb[(size_t)(t0 + r) * 1024 + f0 + c0 + 8] = s1;
    __syncthreads();
    int fr = tid >> 2, tc0 = (tid & 3) * 16;
    half8 o0, o1;
#pragma unroll
    for (int j = 0; j < 8; j++) { o0[j] = lt[tc0 + j][fr]; o1[j] = lt[tc0 + 8 + j][fr]; }
    *(half8*)&histT[(size_t)(f0 + fr) * TALL + t0 + tc0] = o0;
    *(half8*)&histT[(size_t)(f0 + fr) * TALL + t0 + tc0 + 8] = o1;
  }
}

// ---------------- R9 128x128 core (kept for wpack/G/FO) -------------------
__device__ __forceinline__ void gemm_core(const _Float16* __restrict__ A, size_t lda,
                                          const _Float16* __restrict__ B, size_t ldb,
                                          int kIters, _Float16* As, _Float16* Bs,
                                          int tid, floatx4 acc[4][4]) {
  int lane = tid & 63, w = tid >> 6;
  int l15 = lane & 15, quad = lane >> 4;
  int wm = (w >> 1) * 64, wn = (w & 1) * 64;
  int swz = ((tid & 3) ^ ((tid >> 3) & 3)) * 8;
  int pch = (quad ^ ((l15 >> 1) & 3)) * 8;
  const char* gA0 = (const char*)(A + (size_t)(tid >> 2) * lda + swz);
  const char* gA1 = (const char*)(A + ((size_t)(tid >> 2) + 64) * lda + swz);
  const char* gB0 = (const char*)(B + (size_t)(tid >> 2) * ldb + swz);
  const char* gB1 = (const char*)(B + ((size_t)(tid >> 2) + 64) * ldb + swz);
  _Float16* lA = As + w * 512;
  _Float16* lB = Bs + w * 512;
#define GC_STAGE(buf, k)                                    \
  do {                                                      \
    size_t off_ = (size_t)(k) * 64;                         \
    gl_lds16(gA0 + off_, lA + (buf) * 4096);                \
    gl_lds16(gA1 + off_, lA + (buf) * 4096 + 2048);         \
    gl_lds16(gB0 + off_, lB + (buf) * 4096);                \
    gl_lds16(gB1 + off_, lB + (buf) * 4096 + 2048);         \
  } while (0)
#define GC_STEP(buf, k)                                                       \
  do {                                                                        \
    if ((k) + 1 < kIters) asm volatile("s_waitcnt vmcnt(4)" ::: "memory");    \
    else                  asm volatile("s_waitcnt vmcnt(0)" ::: "memory");    \
    asm volatile("s_barrier" ::: "memory");                                   \
    const _Float16* Ac_ = As + (buf) * 4096;                                  \
    const _Float16* Bc_ = Bs + (buf) * 4096;                                  \
    half8 a_[4];                                                              \
    _Pragma("unroll")                                                         \
    for (int mi = 0; mi < 4; mi++)                                            \
      a_[mi] = *(const half8*)&Ac_[(wm + mi * 16 + l15) * 32 + pch];          \
    _Pragma("unroll")                                                         \
    for (int ni = 0; ni < 4; ni++) {                                          \
      half8 b8_ = *(const half8*)&Bc_[(wn + ni * 16 + l15) * 32 + pch];       \
      _Pragma("unroll")                                                       \
      for (int mi = 0; mi < 4; mi++)                                          \
        acc[mi][ni] = __builtin_amdgcn_mfma_f32_16x16x32_f16(a_[mi], b8_,     \
                                                             acc[mi][ni], 0, 0, 0); \
    }                                                                         \
    asm volatile("s_waitcnt lgkmcnt(0)" ::: "memory");                        \
    asm volatile("s_barrier" ::: "memory");                                   \
    if ((k) + 2 < kIters) GC_STAGE(buf, (k) + 2);                             \
  } while (0)
  GC_STAGE(0, 0);
  GC_STAGE(1, 1);
  for (int kk = 0; kk < kIters; kk += 2) {
    GC_STEP(0, kk);
    GC_STEP(1, kk + 1);
  }
#undef GC_STEP
#undef GC_STAGE
}

// ---------------- 256x256 8-wave BK=32 cross-tile-pipelined core ----------
// nT fixed at 32. 4 bufs, depth-3 counted vmcnt (identical ledger to R17).
// Per tile t: issue RD A-hi(t) [buf t, certified at iter t-1's barrier];
// vmcnt(4|0) + barrier [certify buf t+1]; issue RD B/A-lo(t+1) into the
// ALTERNATE reg set; issue stage(t+3); MFMA tile t from regs. Compiler
// emits lgkmcnt(12) before MFMA-lo and lgkmcnt(8) before MFMA-hi -> the
// 12 newer reads stay in flight UNDER the MFMA burst (time/tile ->
// max(LDS,MFMA) not sum). WAR: stage(t+3) hits buf(t-1); its reads were
// drained by iter t-1's pre-MFMA waits, 2 barriers earlier. ONE barrier
// per tile. MFMA order per acc identical to R17 (lo cluster then hi).
template <typename OFF>
__device__ __forceinline__ void gemm256_pipe(const _Float16* __restrict__ A, size_t lda,
                                             const _Float16* __restrict__ B, size_t ldb,
                                             OFF off, _Float16* As, _Float16* Bs,
                                             int tid, floatx4 acc[8][4]) {
  int lane = tid & 63, w = tid >> 6;
  int l15 = lane & 15, quad = lane >> 4;
  int wr = w >> 2, wc = w & 3;
  int pch = (quad ^ ((l15 >> 1) & 3)) * 8;
  int srow = tid >> 2;
  int schunk = (tid & 3) ^ ((tid >> 3) & 3);
  const char* gA0 = (const char*)(A + (size_t)srow * lda + schunk * 8);
  const char* gA1 = (const char*)(A + (size_t)(srow + 128) * lda + schunk * 8);
  const char* gB0 = (const char*)(B + (size_t)srow * ldb + schunk * 8);
  const char* gB1 = (const char*)(B + (size_t)(srow + 128) * ldb + schunk * 8);
  _Float16* lA = As + w * 512;
  _Float16* lB = Bs + w * 512;
  half8 B0[4], A0[4], B1[4], A1[4], Ah[4];
#define P_ST(buf, t)                                          \
  do { size_t o_ = off(t);                                    \
    gl_lds16(gA0 + o_, lA + (buf) * 8192);                    \
    gl_lds16(gA1 + o_, lA + (buf) * 8192 + 4096);             \
    gl_lds16(gB0 + o_, lB + (buf) * 8192);                    \
    gl_lds16(gB1 + o_, lB + (buf) * 8192 + 4096);             \
  } while (0)
#define P_RDM(BN, AN, buf)                                                     \
  do {                                                                         \
    const _Float16* Ac_ = As + (buf) * 8192;                                   \
    const _Float16* Bc_ = Bs + (buf) * 8192;                                   \
    _Pragma("unroll")                                                          \
    for (int ni = 0; ni < 4; ni++)                                             \
      BN[ni] = *(const half8*)&Bc_[(wc * 64 + ni * 16 + l15) * 32 + pch];      \
    _Pragma("unroll")                                                          \
    for (int mi = 0; mi < 4; mi++)                                             \
      AN[mi] = *(const half8*)&Ac_[(wr * 128 + mi * 16 + l15) * 32 + pch];     \
  } while (0)
#define P_RDH(buf)                                                             \
  do {                                                                         \
    const _Float16* Ac_ = As + (buf) * 8192;                                   \
    _Pragma("unroll")                                                          \
    for (int mi = 0; mi < 4; mi++)                                             \
      Ah[mi] = *(const half8*)&Ac_[(wr * 128 + 64 + mi * 16 + l15) * 32 + pch];\
  } while (0)
#define P_MM(CB, CA)                                                           \
  do {                                                                         \
    __builtin_amdgcn_s_setprio(1);                                             \
    _Pragma("unroll")                                                          \
    for (int mi = 0; mi < 4; mi++)                                             \
      _Pragma("unroll")                                                        \
      for (int ni = 0; ni < 4; ni++)                                           \
        acc[mi][ni] = __builtin_amdgcn_mfma_f32_16x16x32_f16(CA[mi], CB[ni], acc[mi][ni], 0, 0, 0); \
    _Pragma("unroll")                                                          \
    for (int mi = 0; mi < 4; mi++)                                             \
      _Pragma("unroll")                                                        \
      for (int ni = 0; ni < 4; ni++)                                           \
        acc[4 + mi][ni] = __builtin_amdgcn_mfma_f32_16x16x32_f16(Ah[mi], CB[ni], acc[4 + mi][ni], 0, 0, 0); \
    __builtin_amdgcn_s_setprio(0);                                             \
  } while (0)
#define P_STEP(CB, CA, NB, NA, t)                                              \
  do {                                                                         \
    P_RDH((t) & 3);                                                            \
    if ((t) + 1 < 32) {                                                        \
      if ((t) + 2 < 32) asm volatile("s_waitcnt vmcnt(4)" ::: "memory");       \
      else              asm volatile("s_waitcnt vmcnt(0)" ::: "memory");       \
      asm volatile("s_barrier" ::: "memory");                                  \
      P_RDM(NB, NA, ((t) + 1) & 3);                                            \
      if ((t) + 3 < 32) P_ST(((t) + 3) & 3, (t) + 3);                          \
    }                                                                          \
    P_MM(CB, CA);                                                              \
  } while (0)
  P_ST(0, 0); P_ST(1, 1); P_ST(2, 2);
  asm volatile("s_waitcnt vmcnt(8)" ::: "memory");
  asm volatile("s_barrier" ::: "memory");
  P_RDM(B0, A0, 0);
  for (int t = 0; t < 32; t += 2) {
    P_STEP(B0, A0, B1, A1, t);
    P_STEP(B1, A1, B0, A0, t + 1);
  }
#undef P_STEP
#undef P_MM
#undef P_RDH
#undef P_RDM
#undef P_ST
}

// ---------------- generic single-B GEMM (R9 core) ----------------
template <bool OUTF32>
__launch_bounds__(256, 3)
__global__ void gemm_f16_kernel(const _Float16* __restrict__ A, size_t lda, size_t aoffz,
                                const _Float16* __restrict__ B, size_t ldb, size_t boffz,
                                int kIters, const float* __restrict__ bias, size_t biasoffz,
                                float scale, void* __restrict__ C, size_t ldc, size_t coffz) {
  __shared__ __align__(16) _Float16 As[8192];
  __shared__ __align__(16) _Float16 Bs[8192];
  int tid = threadIdx.x;
  const _Float16* Ab = A + aoffz * blockIdx.z + (size_t)(blockIdx.y * 128) * lda;
  const _Float16* Bb = B + boffz * blockIdx.z + (size_t)(blockIdx.x * 128) * ldb;
  floatx4 acc[4][4];
  floatx4 zero = {0.f, 0.f, 0.f, 0.f};
#pragma unroll
  for (int a = 0; a < 4; a++)
#pragma unroll
    for (int b = 0; b < 4; b++) acc[a][b] = zero;
  gemm_core(Ab, lda, Bb, ldb, kIters, As, Bs, tid, acc);
  int lane = tid & 63, w = tid >> 6;
  int l15 = lane & 15, quad = lane >> 4;
  int wm = (w >> 1) * 64, wn = (w & 1) * 64;
#pragma unroll
  for (int mi = 0; mi < 4; mi++)
#pragma unroll
    for (int ni = 0; ni < 4; ni++) {
      int colg = blockIdx.x * 128 + wn + ni * 16 + l15;
      float bv = bias ? bias[biasoffz * blockIdx.z + colg] : 0.f;
#pragma unroll
      for (int r = 0; r < 4; r++) {
        int rowg = blockIdx.y * 128 + wm + mi * 16 + quad * 4 + r;
        float v = (acc[mi][ni][r] + bv) * scale;
        size_t idx = coffz * blockIdx.z + (size_t)rowg * ldc + colg;
        if (OUTF32) ((float*)C)[idx] = v;
        else ((_Float16*)C)[idx] = (_Float16)v;
      }
    }
}

// ---------------- wpack (unchanged, R9 core) ----------------
__launch_bounds__(256, 3)
__global__ void wpack_kernel(const _Float16* __restrict__ WoT, const _Float16* __restrict__ Wv16,
                             const _Float16* __restrict__ Wk16, const _Float16* __restrict__ Wq16,
                             const float* __restrict__ bv, const float* __restrict__ bq,
                             _Float16* __restrict__ WVOT, _Float16* __restrict__ WQKT,
                             float* __restrict__ bvwo, float* __restrict__ bqk) {
  __shared__ __align__(16) _Float16 As[8192];
  __shared__ __align__(16) _Float16 Bs[8192];
  int bid = blockIdx.x, tid = threadIdx.x;
  if (bid < 512) {
    bool isQK = bid >= 256;
    int g = bid & 255;
    int x = g & 7, y = (g >> 3) & 7, z = g >> 6;
    const _Float16* A = isQK ? Wk16 : WoT;
    const _Float16* B = isQK ? Wq16 : Wv16;
    const _Float16* Ab = A + 256 * z + (size_t)(y * 128) * 1024;
    const _Float16* Bb = B + 256 * z + (size_t)(x * 128) * 1024;
    floatx4 acc[4][4];
    floatx4 zero = {0.f, 0.f, 0.f, 0.f};
#pragma unroll
    for (int a = 0; a < 4; a++)
#pragma unroll
      for (int b = 0; b < 4; b++) acc[a][b] = zero;
    gemm_core(Ab, 1024, Bb, 1024, 8, As, Bs, tid, acc);
    float scale = isQK ? 0.0625f : 1.0f;
    _Float16* C = isQK ? WQKT : WVOT;
    size_t ldc = isQK ? 1024 : 4096;
    size_t zoff = isQK ? (size_t)1048576 * z : (size_t)1024 * z;
    int lane = tid & 63, w = tid >> 6;
    int l15 = lane & 15, quad = lane >> 4;
    int wm = (w >> 1) * 64, wn = (w & 1) * 64;
#pragma unroll
    for (int mi = 0; mi < 4; mi++)
#pragma unroll
      for (int ni = 0; ni < 4; ni++) {
        int col = x * 128 + wn + ni * 16 + l15;
#pragma unroll
        for (int r = 0; r < 4; r++) {
          int row = y * 128 + wm + mi * 16 + quad * 4 + r;
          C[zoff + (size_t)row * ldc + col] = (_Float16)(acc[mi][ni][r] * scale);
        }
      }
  } else if (bid < 516) {
    int j = (bid - 512) * 256 + tid;
    const half8* row = (const half8*)(WoT + (size_t)j * 1024);
    float a = 0.f;
    for (int c = 0; c < 128; c++) {
      half8 w8 = row[c];
#pragma unroll
      for (int e = 0; e < 8; e++) a += bv[c * 8 + e] * (float)w8[e];
    }
    bvwo[j] = a;
  } else {
    int idx = (bid - 516) * 256 + tid;
    int h = idx >> 10, f = idx & 1023;
    const _Float16* row = Wk16 + (size_t)f * 1024 + h * 256;
    float a = 0.f;
    for (int n = 0; n < 256; n++) a += bq[h * 256 + n] * (float)row[n];
    bqk[idx] = a * 0.0625f;
  }
}

// ---------------- S gemm: pipelined 256^2 core + exp epilogue + Zframe ----
__launch_bounds__(512, 2)
__global__ void gemm256_s_kernel(const _Float16* __restrict__ G, const _Float16* __restrict__ histb,
                                 _Float16* __restrict__ Eout, float* __restrict__ zframe) {
  __shared__ __align__(16) _Float16 SM[65536];
  _Float16* As = SM;
  _Float16* Bs = SM + 32768;
  int bid = blockIdx.x, tid = threadIdx.x;
  int h = bid >> 6, nt = bid & 63;
  const _Float16* Ab = G + (size_t)h * 262144;
  const _Float16* Bb = histb + (size_t)(nt * 256) * 1024;
  floatx4 acc[8][4];
  floatx4 zero = {0.f, 0.f, 0.f, 0.f};
#pragma unroll
  for (int a = 0; a < 8; a++)
#pragma unroll
    for (int b = 0; b < 4; b++) acc[a][b] = zero;
  gemm256_pipe(Ab, 1024, Bb, 1024, LinOff{}, As, Bs, tid, acc);
  int lane = tid & 63, w = tid >> 6;
  int l15 = lane & 15, quad = lane >> 4;
  int wr = w >> 2, wc = w & 3;
  __syncthreads();                       // K-loop LDS dead
#pragma unroll
  for (int mh = 0; mh < 2; mh++)
#pragma unroll
    for (int mi = 0; mi < 4; mi++)
#pragma unroll
      for (int ni = 0; ni < 4; ni++) {
        int col = wc * 64 + ni * 16 + l15;
#pragma unroll
        for (int r = 0; r < 4; r++) {
          int row = wr * 128 + mh * 64 + mi * 16 + quad * 4 + r;
          int colsw = col ^ (((row >> 2) & 3) << 3);
          SM[row * 256 + colsw] = (_Float16)__expf(acc[mh * 4 + mi][ni][r]);
        }
      }
  __syncthreads();
  int c32 = lane & 31, hs = lane >> 5;
#pragma unroll
  for (int it = 0; it < 16; it++) {
    int row = w * 32 + it * 2 + hs;
    int cs = (c32 * 8) ^ (((row >> 2) & 3) << 3);   // physical LDS position
    half8 v = *(const half8*)&SM[row * 256 + cs];   // holds LOGICAL cols [c32*8, +8)
    float s = 0.f;
#pragma unroll
    for (int j = 0; j < 8; j++) s += (float)v[j];
#pragma unroll
    for (int off = 1; off <= 16; off <<= 1) s += __shfl_xor(s, off, 64);
    *(half8*)&Eout[(size_t)h * 4194304 + (size_t)row * TALL + nt * 256 + c32 * 8] = v;
    if (c32 == 0) zframe[(size_t)(h * 256 + row) * 64 + nt] = s;
  }
}

// ---------------- csoftmax: Zframe(256KB) -> w4 class-weight table --------
__global__ void csoftmax_kernel(const float* __restrict__ zframe, const float* __restrict__ dil_w,
                                float* __restrict__ w4) {
  int row = blockIdx.x * 256 + threadIdx.x;
  const float* z = zframe + (size_t)row * 64;
  float z1 = 0.f, z4 = 0.f, z8 = 0.f, z16 = 0.f;
#pragma unroll
  for (int f = 0; f < 64; f++) {
    float v = z[f];
    z1 += v;
    if (!(f & 3))  z4 += v;
    if (!(f & 7))  z8 += v;
    if (!(f & 15)) z16 += v;
  }
  float w0 = dil_w[0], w1 = dil_w[1], w2 = dil_w[2], w3 = dil_w[3];
  float wmx = fmaxf(fmaxf(w0, w1), fmaxf(w2, w3));
  float e0 = __expf(w0 - wmx), e1 = __expf(w1 - wmx), e2 = __expf(w2 - wmx), e3 = __expf(w3 - wmx);
  float wsum = e0 + e1 + e2 + e3;
  float b0 = (e0 / wsum) / z1 * 256.0f;
  float b1 = (e1 / wsum) / z4 * 256.0f;
  float b2 = (e2 / wsum) / z8 * 256.0f;
  float b3 = (e3 / wsum) / z16 * 256.0f;
  float* wr = w4 + (size_t)row * 4;
  wr[0] = b0;
  wr[1] = b0 + b1;
  wr[2] = b0 + b1 + b2;
  wr[3] = b0 + b1 + b2 + b3;
}

// ---------------- PH gemm: pipelined 256^2 core, frame-class chunks -------
__launch_bounds__(512, 2)
__global__ void gemm256_ph_kernel(const _Float16* __restrict__ E, const _Float16* __restrict__ histT,
                                  char* __restrict__ ws) {
  __shared__ __align__(16) _Float16 SM[65536];
  _Float16* As = SM;
  _Float16* Bs = SM + 32768;
  int bid = blockIdx.x, tid = threadIdx.x;
  int xcd = bid & 7, slot = bid >> 3;
  int g = xcd + 8 * (slot >> 4);
  int member = slot & 15;
  int h = member >> 2, nt = member & 3;
  const _Float16* A = E + (size_t)h * 4194304;
  const _Float16* B = histT + (size_t)(nt * 256) * TALL;
  floatx4 acc[8][4];
  floatx4 zero = {0.f, 0.f, 0.f, 0.f};
#pragma unroll
  for (int a = 0; a < 8; a++)
#pragma unroll
    for (int b = 0; b < 4; b++) acc[a][b] = zero;
  gemm256_pipe(A, TALL, B, TALL, ClsOff{g}, As, Bs, tid, acc);
  int lane = tid & 63, w = tid >> 6;
  int l15 = lane & 15, quad = lane >> 4;
  int wr = w >> 2, wc = w & 3;
  // ---- epilogue: swizzled LDS transpose, LOGICAL-column global stores ----
  __syncthreads();
#pragma unroll
  for (int mh = 0; mh < 2; mh++)
#pragma unroll
    for (int mi = 0; mi < 4; mi++)
#pragma unroll
      for (int ni = 0; ni < 4; ni++) {
        int col = wc * 64 + ni * 16 + l15;
#pragma unroll
        for (int r = 0; r < 4; r++) {
          int row = wr * 128 + mh * 64 + mi * 16 + quad * 4 + r;
          int colsw = col ^ (((row >> 2) & 3) << 3);
          SM[row * 256 + colsw] = (_Float16)acc[mh * 4 + mi][ni][r];
        }
      }
  __syncthreads();
  _Float16* chunk = (_Float16*)(ws + chunk16_off(g));
  int c32 = lane & 31, hs = lane >> 5;
  int colbase = h * 1024 + nt * 256;
#pragma unroll
  for (int it = 0; it < 16; it++) {
    int row = w * 32 + it * 2 + hs;
    int cs = (c32 * 8) ^ (((row >> 2) & 3) << 3);   // physical LDS position
    half8 v = *(const half8*)&SM[row * 256 + cs];   // logical cols [c32*8, +8)
    *(half8*)&chunk[(size_t)row * 4096 + colbase + c32 * 8] = v;
  }
}

// ---------------- reduce: 4 class sums x per-(h,q) weights -> PHred -------
__global__ void reduce_ph_kernel(const char* __restrict__ ws, const float* __restrict__ w4,
                                 _Float16* __restrict__ PHred) {
  size_t e8 = ((size_t)blockIdx.x * 256 + threadIdx.x) * 8;
  int q = (int)(e8 >> 12);
  int h = (int)((e8 >> 10) & 3);
  const float* wr = w4 + (size_t)(h * 256 + q) * 4;
  float sA[8] = {0,0,0,0,0,0,0,0}, sB[8] = {0,0,0,0,0,0,0,0};
  float sC[8] = {0,0,0,0,0,0,0,0}, sD[8] = {0,0,0,0,0,0,0,0};
#pragma unroll
  for (int g = 0; g < 12; g++) {
    const _Float16* p = (const _Float16*)(ws + chunk16_off(g));
    half8 v = *(const half8*)&p[e8];
#pragma unroll
    for (int j = 0; j < 8; j++) sA[j] += (float)v[j];
  }
#pragma unroll
  for (int g = 12; g < 14; g++) {
    const _Float16* p = (const _Float16*)(ws + chunk16_off(g));
    half8 v = *(const half8*)&p[e8];
#pragma unroll
    for (int j = 0; j < 8; j++) sB[j] += (float)v[j];
  }
  {
    const _Float16* p = (const _Float16*)(ws + chunk16_off(14));
    half8 v = *(const half8*)&p[e8];
#pragma unroll
    for (int j = 0; j < 8; j++) sC[j] += (float)v[j];
  }
  {
    const _Float16* p = (const _Float16*)(ws + chunk16_off(15));
    half8 v = *(const half8*)&p[e8];
#pragma unroll
    for (int j = 0; j < 8; j++) sD[j] += (float)v[j];
  }
  float wA = wr[0], wB = wr[1], wC = wr[2], wD = wr[3];
  half8 o;
#pragma unroll
  for (int j = 0; j < 8; j++)
    o[j] = (_Float16)(wA * sA[j] + wB * sB[j] + wC * sC[j] + wD * sD[j]);
  *(half8*)&PHred[e8] = o;
}

// ---------------- FO 8-way reduce + bo + bv@Wo + residual + layernorm ------
__global__ void ln_kernel(const float* __restrict__ x, const float* __restrict__ part2,
                          const float* __restrict__ bo, const float* __restrict__ bvwo,
                          const float* __restrict__ gamma, const float* __restrict__ beta,
                          float* __restrict__ out) {
  int b = blockIdx.x, t = threadIdx.x;
  __shared__ float red[8];
  float y[4];
  float sum = 0.f, sq = 0.f;
#pragma unroll
  for (int i = 0; i < 4; i++) {
    int j = t + i * 256;
    float v = x[(size_t)b * 1024 + j] + bo[j] + bvwo[j];
#pragma unroll
    for (int z = 0; z < 8; z++) v += part2[(size_t)z * 262144 + (size_t)b * 1024 + j];
    y[i] = v;
    sum += v;
    sq += v * v;
  }
#pragma unroll
  for (int off = 1; off < 64; off <<= 1) {
    sum += __shfl_xor(sum, off, 64);
    sq += __shfl_xor(sq, off, 64);
  }
  int w = t >> 6, lane = t & 63;
  if (lane == 0) { red[w] = sum; red[4 + w] = sq; }
  __syncthreads();
  sum = red[0] + red[1] + red[2] + red[3];
  sq = red[4] + red[5] + red[6] + red[7];
  float mu = sum * (1.f / 1024.f);
  float var = sq * (1.f / 1024.f) - mu * mu;
  float inv = rsqrtf(var + 1e-5f);
#pragma unroll
  for (int i = 0; i < 4; i++) {
    int j = t + i * 256;
    out[(size_t)b * 1024 + j] = (y[i] - mu) * inv * gamma[j] + beta[j];
  }
}

// ---------------- host launch ----------------
extern "C" void kernel_launch(void* const* d_in, const int* in_sizes, int n_in,
                              void* d_out, int out_size, void* d_ws, size_t ws_size,
                              hipStream_t stream) {
  const float* x     = (const float*)d_in[0];
  const float* hist  = (const float*)d_in[1];
  const float* Wq    = (const float*)d_in[2];
  const float* bq    = (const float*)d_in[3];
  const float* Wk    = (const float*)d_in[4];
  // bk (d_in[5]) dropped exactly: softmax shift invariance.
  const float* Wv    = (const float*)d_in[6];
  const float* bv    = (const float*)d_in[7];
  const float* Wo    = (const float*)d_in[8];
  const float* bo    = (const float*)d_in[9];
  const float* dil_w = (const float*)d_in[10];
  const float* gamma = (const float*)d_in[11];
  const float* beta  = (const float*)d_in[12];
  char* ws = (char*)d_ws;

  _Float16* WoT   = (_Float16*)(ws + OFF_WOT);
  _Float16* Wv16  = (_Float16*)(ws + OFF_WV16);
  _Float16* Wk16  = (_Float16*)(ws + OFF_WK16);
  _Float16* Wq16  = (_Float16*)(ws + OFF_WQ16);
  _Float16* xb    = (_Float16*)(ws + OFF_XB);
  _Float16* G     = (_Float16*)(ws + OFF_G);
  _Float16* WVOT  = (_Float16*)(ws + OFF_WVOT);
  _Float16* WQKT  = (_Float16*)(ws + OFF_WQKT);
  float* bvwo     = (float*)(ws + OFF_BVWO);
  float* bqk      = (float*)(ws + OFF_BQK);
  _Float16* PHred = (_Float16*)(ws + OFF_PHR);
  float* oppart   = (float*)(ws + OFF_OPP);
  _Float16* histb = (_Float16*)(ws + OFF_HB);
  _Float16* histT = (_Float16*)(ws + OFF_HT);
  _Float16* Eb    = (_Float16*)(ws + OFF_S);
  float* zframe   = (float*)(ws + OFF_WQKT);   // 256 KB; WQKT dead after G, read before PH chunks overwrite
  float* w4       = (float*)(ws + OFF_G);      // 16 KB; G dead after S

  // 1) prep: WoT, Wv/Wk/Wq/x cvt, hist -> histb + histT (single hist read)
  prep_kernel<<<dim3(8448), 256, 0, stream>>>(Wo, Wv, Wk, Wq, x, hist,
                                              WoT, Wv16, Wk16, Wq16, xb, histb, histT);
  // 2) wpack: WVOT + WQKT + bvwo + bqk in one launch
  wpack_kernel<<<dim3(532), 256, 0, stream>>>(WoT, Wv16, Wk16, Wq16, bv, bq,
                                              WVOT, WQKT, bvwo, bqk);
  // 3) G[h] = x @ WQKT_h^T + bqk_h  (scale 1/16 pre-folded)
  gemm_f16_kernel<false><<<dim3(8, 2, 4), 256, 0, stream>>>(
      xb, 1024, 0, WQKT, 1024, 1048576, 32, bqk, 1024, 1.0f, (void*)G, 1024, 262144);
  // 4) E[h] = exp(G_h @ hist^T) + Zframe row/frame sums (pipelined core)
  gemm256_s_kernel<<<dim3(256), 512, 0, stream>>>(G, histb, Eb, zframe);
  // 5) csoftmax: Zframe -> w4 class-weight table
  csoftmax_kernel<<<dim3(4), 256, 0, stream>>>(zframe, dil_w, w4);
  // 6) PH class-partials = E_h @ hist (pipelined core, frame-class chunks)
  gemm256_ph_kernel<<<dim3(256), 512, 0, stream>>>(Eb, histT, ws);
  // 7) reduce: 4 class sums x w4 weights -> PHred
  reduce_ph_kernel<<<dim3(512), 256, 0, stream>>>(ws, w4, PHred);
  // 8) FO partials = PHred @ WVOT^T (split-K 8; scale 1/256)
  gemm_f16_kernel<true><<<dim3(8, 2, 8), 256, 0, stream>>>(
      PHred, 4096, 512, WVOT, 4096, 512, 16, nullptr, 0, 1.0f / 256.0f,
      (void*)oppart, 1024, 262144);
  // 9) 8-way reduce + bo + bv@Wo + residual + layernorm
  ln_kernel<<<dim3(256), 256, 0, stream>>>(x, oppart, bo, bvwo, gamma, beta, (float*)d_out);
}

// Round 14
// 302.597 us; speedup vs baseline: 1.0509x; 1.0509x over previous
//
#include <hip/hip_runtime.h>

// TemporalDilatedAttention on gfx950 — round 20
// vs R19 (FAILED absmax 0.206): folding csoftmax into PH (block 256) raced:
// zframe lived at OFF_WQKT == PH chunks g=4..7's bytes; block 256 read it
// while g=4..7 blocks overwrote it IN THE SAME LAUNCH (R17 was safe only
// because csoftmax was a separate earlier launch). Fix: zframe moved to the
// OFF_PHR region (dead from S until reduce_ph, which is stream-ordered
// after PH; no chunk overlaps PHR). Keeps R19's grid-shape wins:
// G split-K-4 (64->256 blocks), FO split-16 (128->256 blocks), csoftmax
// folded into PH. All GEMM cores/epilogues identical to R17 (best, 309.7us).

#define DD    1024
#define TALL  16384

typedef _Float16 half8  __attribute__((ext_vector_type(8)));
typedef _Float16 half4v __attribute__((ext_vector_type(4)));
typedef float    floatx4 __attribute__((ext_vector_type(4)));
typedef unsigned int u32;

// ---------------- workspace layout (bytes), ~132.5 MB ----------------
static const size_t OFF_WOT  = 0;          // 2 MB  Wo^T f16
static const size_t OFF_WV16 = 2097152;    // 2 MB  Wv f16
static const size_t OFF_WK16 = 4194304;    // 2 MB  Wk f16
static const size_t OFF_WQ16 = 6291456;    // 2 MB  Wq f16
static const size_t OFF_XB   = 8388608;    // 0.5 MB x f16
static const size_t OFF_G    = 8912896;    // 2 MB  G f16; w4 table after S
static const size_t OFF_WVOT = 11010048;   // 8 MB  WVOT f16 (LIVE through FO)
static const size_t OFF_WQKT = 19398656;   // 8 MB  WQKT f16 (dead after G; chunks 4-7 here)
static const size_t OFF_BVWO = 27787264;   // 4 KB  bv@Wo f32
static const size_t OFF_BQK  = 27791360;   // 16 KB bqk f32
static const size_t OFF_PHR  = 27807744;   // 2 MB  zframe (S->PH), then PHred f16
static const size_t OFF_OPP  = 29904896;   // 16 MB FO partials f32 (spills into dead histb head)
static const size_t OFF_HB   = 38293504;   // 32 MB histb (dead after S)
static const size_t OFF_HT   = 71848960;   // 32 MB hist^T f16 [feat][t]
static const size_t OFF_S    = 105403392;  // 32 MB: G split-K partials (16MB) then E f16

// PH f16 partial chunks: 16 x 2 MB over regions dead during launches 5-6.
__device__ __forceinline__ size_t chunk16_off(int g) {
  if (g < 4)  return (size_t)g * 2097152;
  if (g < 8)  return 19398656 + (size_t)(g - 4) * 2097152;
  if (g < 12) return 29904896 + (size_t)(g - 8) * 2097152;
  return 38293504 + (size_t)(g - 12) * 2097152;
}

// Frame-class chunk map: chunk g, sub-frame j (0..3) -> frame index.
__device__ __forceinline__ int frame_of(int g, int j) {
  if (g < 12) { int m = g * 4 + j; return m + m / 3 + 1; }
  if (g < 14) return 4 + 8 * ((g - 12) * 4 + j);
  if (g == 14) return 8 + 16 * j;
  return 16 * j;
}
__device__ __forceinline__ size_t foff(int g, int t) {
  return (size_t)frame_of(g, t >> 3) * 512 + (size_t)(t & 7) * 64;
}

// ---------------- async global->LDS, 16B per lane ----------------
__device__ __forceinline__ void gl_lds16(const void* g, void* l) {
  __builtin_amdgcn_global_load_lds((const __attribute__((address_space(1))) u32*)g,
                                   (__attribute__((address_space(3))) u32*)l, 16, 0, 0);
}

// ---------------- prep (unchanged) ----------------
__global__ void prep_kernel(const float* __restrict__ Wo, const float* __restrict__ Wv,
                            const float* __restrict__ Wk, const float* __restrict__ Wq,
                            const float* __restrict__ x, const float* __restrict__ hist,
                            _Float16* __restrict__ WoT, _Float16* __restrict__ Wv16,
                            _Float16* __restrict__ Wk16, _Float16* __restrict__ Wq16,
                            _Float16* __restrict__ xb, _Float16* __restrict__ histb,
                            _Float16* __restrict__ histT) {
  int bid = blockIdx.x, tid = threadIdx.x;
  if (bid < 1024) {                        // Wo transpose+cvt
    int k0 = (bid & 31) * 32, n0 = (bid >> 5) * 32;
    __shared__ float t32[32][33];
    int tx = tid & 31, ty = tid >> 5;
#pragma unroll
    for (int i = 0; i < 4; i++) {
      int r = ty + i * 8;
      t32[r][tx] = Wo[(size_t)(k0 + r) * DD + n0 + tx];
    }
    __syncthreads();
#pragma unroll
    for (int i = 0; i < 4; i++) {
      int r = ty + i * 8;
      WoT[(size_t)(n0 + r) * DD + k0 + tx] = (_Float16)t32[tx][r];
    }
  } else if (bid < 4352) {                 // plain cvt
    const float* src; _Float16* dst; size_t i;
    if (bid < 2048)      { src = Wv; dst = Wv16; i = (size_t)(bid - 1024) * 256 + tid; }
    else if (bid < 3072) { src = Wk; dst = Wk16; i = (size_t)(bid - 2048) * 256 + tid; }
    else if (bid < 4096) { src = Wq; dst = Wq16; i = (size_t)(bid - 3072) * 256 + tid; }
    else                 { src = x;  dst = xb;   i = (size_t)(bid - 4096) * 256 + tid; }
    float4 v = ((const float4*)src)[i];
    half4v h = {(_Float16)v.x, (_Float16)v.y, (_Float16)v.z, (_Float16)v.w};
    *(half4v*)(dst + 4 * i) = h;
  } else {                                 // hist dual write
    int tb = bid - 4352;
    int t0 = (tb & 255) * 64, f0 = (tb >> 8) * 64;
    __shared__ _Float16 lt[64][72];
    int r = tid >> 2, c0 = (tid & 3) * 16;
    half8 s0, s1;
#pragma unroll
    for (int i = 0; i < 4; i++) {
      float4 v = *(const float4*)&hist[(size_t)(t0 + r) * 1024 + f0 + c0 + i * 4];
      half4v h = {(_Float16)v.x, (_Float16)v.y, (_Float16)v.z, (_Float16)v.w};
      *(half4v*)&lt[r][c0 + i * 4] = h;
      if (i < 2) { s0[i*4]=h[0]; s0[i*4+1]=h[1]; s0[i*4+2]=h[2]; s0[i*4+3]=h[3]; }
      else { s1[(i-2)*4]=h[0]; s1[(i-2)*4+1]=h[1]; s1[(i-2)*4+2]=h[2]; s1[(i-2)*4+3]=h[3]; }
    }
    *(half8*)&histb[(size_t)(t0 + r) * 1024 + f0 + c0] = s0;
    *(half8*)&histb[(size_t)(t0 + r) * 1024 + f0 + c0 + 8] = s1;
    __syncthreads();
    int fr = tid >> 2, tc0 = (tid & 3) * 16;
    half8 o0, o1;
#pragma unroll
    for (int j = 0; j < 8; j++) { o0[j] = lt[tc0 + j][fr]; o1[j] = lt[tc0 + 8 + j][fr]; }
    *(half8*)&histT[(size_t)(f0 + fr) * TALL + t0 + tc0] = o0;
    *(half8*)&histT[(size_t)(f0 + fr) * TALL + t0 + tc0 + 8] = o1;
  }
}

// ---------------- R9 128x128 core (wpack/G/FO) ----------------------------
__device__ __forceinline__ void gemm_core(const _Float16* __restrict__ A, size_t lda,
                                          const _Float16* __restrict__ B, size_t ldb,
                                          int kIters, _Float16* As, _Float16* Bs,
                                          int tid, floatx4 acc[4][4]) {
  int lane = tid & 63, w = tid >> 6;
  int l15 = lane & 15, quad = lane >> 4;
  int wm = (w >> 1) * 64, wn = (w & 1) * 64;
  int swz = ((tid & 3) ^ ((tid >> 3) & 3)) * 8;
  int pch = (quad ^ ((l15 >> 1) & 3)) * 8;
  const char* gA0 = (const char*)(A + (size_t)(tid >> 2) * lda + swz);
  const char* gA1 = (const char*)(A + ((size_t)(tid >> 2) + 64) * lda + swz);
  const char* gB0 = (const char*)(B + (size_t)(tid >> 2) * ldb + swz);
  const char* gB1 = (const char*)(B + ((size_t)(tid >> 2) + 64) * ldb + swz);
  _Float16* lA = As + w * 512;
  _Float16* lB = Bs + w * 512;
#define GC_STAGE(buf, k)                                    \
  do {                                                      \
    size_t off_ = (size_t)(k) * 64;                         \
    gl_lds16(gA0 + off_, lA + (buf) * 4096);                \
    gl_lds16(gA1 + off_, lA + (buf) * 4096 + 2048);         \
    gl_lds16(gB0 + off_, lB + (buf) * 4096);                \
    gl_lds16(gB1 + off_, lB + (buf) * 4096 + 2048);         \
  } while (0)
#define GC_STEP(buf, k)                                                       \
  do {                                                                        \
    if ((k) + 1 < kIters) asm volatile("s_waitcnt vmcnt(4)" ::: "memory");    \
    else                  asm volatile("s_waitcnt vmcnt(0)" ::: "memory");    \
    asm volatile("s_barrier" ::: "memory");                                   \
    const _Float16* Ac_ = As + (buf) * 4096;                                  \
    const _Float16* Bc_ = Bs + (buf) * 4096;                                  \
    half8 a_[4];                                                              \
    _Pragma("unroll")                                                         \
    for (int mi = 0; mi < 4; mi++)                                            \
      a_[mi] = *(const half8*)&Ac_[(wm + mi * 16 + l15) * 32 + pch];          \
    _Pragma("unroll")                                                         \
    for (int ni = 0; ni < 4; ni++) {                                          \
      half8 b8_ = *(const half8*)&Bc_[(wn + ni * 16 + l15) * 32 + pch];       \
      _Pragma("unroll")                                                       \
      for (int mi = 0; mi < 4; mi++)                                          \
        acc[mi][ni] = __builtin_amdgcn_mfma_f32_16x16x32_f16(a_[mi], b8_,     \
                                                             acc[mi][ni], 0, 0, 0); \
    }                                                                         \
    asm volatile("s_waitcnt lgkmcnt(0)" ::: "memory");                        \
    asm volatile("s_barrier" ::: "memory");                                   \
    if ((k) + 2 < kIters) GC_STAGE(buf, (k) + 2);                             \
  } while (0)
  GC_STAGE(0, 0);
  GC_STAGE(1, 1);
  for (int kk = 0; kk < kIters; kk += 2) {
    GC_STEP(0, kk);
    GC_STEP(1, kk + 1);
  }
#undef GC_STEP
#undef GC_STAGE
}

// ---------------- 256x256 8-wave BK=32 phased core (R17, offset functor) --
template <typename OFF>
__device__ __forceinline__ void gemm256_run(const _Float16* __restrict__ A, size_t lda,
                                            const _Float16* __restrict__ B, size_t ldb,
                                            OFF off, _Float16* As, _Float16* Bs,
                                            int tid, floatx4 acc[8][4]) {
  int lane = tid & 63, w = tid >> 6;
  int l15 = lane & 15, quad = lane >> 4;
  int wr = w >> 2, wc = w & 3;
  int pch = (quad ^ ((l15 >> 1) & 3)) * 8;
  int srow = tid >> 2;
  int schunk = (tid & 3) ^ ((tid >> 3) & 3);
  const char* gA0 = (const char*)(A + (size_t)srow * lda + schunk * 8);
  const char* gA1 = (const char*)(A + (size_t)(srow + 128) * lda + schunk * 8);
  const char* gB0 = (const char*)(B + (size_t)srow * ldb + schunk * 8);
  const char* gB1 = (const char*)(B + (size_t)(srow + 128) * ldb + schunk * 8);
  _Float16* lA = As + w * 512;
  _Float16* lB = Bs + w * 512;
#define PSTA(buf, t)                                          \
  do { size_t o_ = off(t);                                    \
    gl_lds16(gA0 + o_, lA + (buf) * 8192);                    \
    gl_lds16(gA1 + o_, lA + (buf) * 8192 + 4096);             \
  } while (0)
#define PSTB(buf, t)                                          \
  do { size_t o_ = off(t);                                    \
    gl_lds16(gB0 + o_, lB + (buf) * 8192);                    \
    gl_lds16(gB1 + o_, lB + (buf) * 8192 + 4096);             \
  } while (0)
  PSTA(0, 0); PSTB(0, 0);
  PSTA(1, 1); PSTB(1, 1);
  PSTA(2, 2); PSTB(2, 2);
  for (int t = 0; t < 32; ++t) {
    int buf = t & 3;
    if (t + 2 < 32)      asm volatile("s_waitcnt vmcnt(8)" ::: "memory");
    else if (t + 1 < 32) asm volatile("s_waitcnt vmcnt(4)" ::: "memory");
    else                 asm volatile("s_waitcnt vmcnt(0)" ::: "memory");
    asm volatile("s_barrier" ::: "memory");
    const _Float16* Ac = As + buf * 8192;
    const _Float16* Bc = Bs + buf * 8192;
    half8 b8[4], a8[4];
#pragma unroll
    for (int ni = 0; ni < 4; ni++)
      b8[ni] = *(const half8*)&Bc[(wc * 64 + ni * 16 + l15) * 32 + pch];
#pragma unroll
    for (int mi = 0; mi < 4; mi++)
      a8[mi] = *(const half8*)&Ac[(wr * 128 + mi * 16 + l15) * 32 + pch];
    if (t + 3 < 32) PSTA((t + 3) & 3, t + 3);
    asm volatile("s_barrier" ::: "memory");
    asm volatile("s_waitcnt lgkmcnt(0)" ::: "memory");
    __builtin_amdgcn_s_setprio(1);
#pragma unroll
    for (int mi = 0; mi < 4; mi++)
#pragma unroll
      for (int ni = 0; ni < 4; ni++)
        acc[mi][ni] = __builtin_amdgcn_mfma_f32_16x16x32_f16(a8[mi], b8[ni], acc[mi][ni], 0, 0, 0);
    __builtin_amdgcn_s_setprio(0);
    asm volatile("s_barrier" ::: "memory");
#pragma unroll
    for (int mi = 0; mi < 4; mi++)
      a8[mi] = *(const half8*)&Ac[(wr * 128 + 64 + mi * 16 + l15) * 32 + pch];
    if (t + 3 < 32) PSTB((t + 3) & 3, t + 3);
    asm volatile("s_barrier" ::: "memory");
    asm volatile("s_waitcnt lgkmcnt(0)" ::: "memory");
    __builtin_amdgcn_s_setprio(1);
#pragma unroll
    for (int mi = 0; mi < 4; mi++)
#pragma unroll
      for (int ni = 0; ni < 4; ni++)
        acc[4 + mi][ni] = __builtin_amdgcn_mfma_f32_16x16x32_f16(a8[mi], b8[ni], acc[4 + mi][ni], 0, 0, 0);
    __builtin_amdgcn_s_setprio(0);
    asm volatile("s_barrier" ::: "memory");
  }
#undef PSTA
#undef PSTB
}

struct LinOff { __device__ __forceinline__ size_t operator()(int t) const { return (size_t)t * 64; } };
struct ClsOff { int g; __device__ __forceinline__ size_t operator()(int t) const { return foff(g, t); } };

// ---------------- generic single-B GEMM (R9 core) ----------------
template <bool OUTF32>
__launch_bounds__(256, 3)
__global__ void gemm_f16_kernel(const _Float16* __restrict__ A, size_t lda, size_t aoffz,
                                const _Float16* __restrict__ B, size_t ldb, size_t boffz,
                                int kIters, const float* __restrict__ bias, size_t biasoffz,
                                float scale, void* __restrict__ C, size_t ldc, size_t coffz) {
  __shared__ __align__(16) _Float16 As[8192];
  __shared__ __align__(16) _Float16 Bs[8192];
  int tid = threadIdx.x;
  const _Float16* Ab = A + aoffz * blockIdx.z + (size_t)(blockIdx.y * 128) * lda;
  const _Float16* Bb = B + boffz * blockIdx.z + (size_t)(blockIdx.x * 128) * ldb;
  floatx4 acc[4][4];
  floatx4 zero = {0.f, 0.f, 0.f, 0.f};
#pragma unroll
  for (int a = 0; a < 4; a++)
#pragma unroll
    for (int b = 0; b < 4; b++) acc[a][b] = zero;
  gemm_core(Ab, lda, Bb, ldb, kIters, As, Bs, tid, acc);
  int lane = tid & 63, w = tid >> 6;
  int l15 = lane & 15, quad = lane >> 4;
  int wm = (w >> 1) * 64, wn = (w & 1) * 64;
#pragma unroll
  for (int mi = 0; mi < 4; mi++)
#pragma unroll
    for (int ni = 0; ni < 4; ni++) {
      int colg = blockIdx.x * 128 + wn + ni * 16 + l15;
      float bv = bias ? bias[biasoffz * blockIdx.z + colg] : 0.f;
#pragma unroll
      for (int r = 0; r < 4; r++) {
        int rowg = blockIdx.y * 128 + wm + mi * 16 + quad * 4 + r;
        float v = (acc[mi][ni][r] + bv) * scale;
        size_t idx = coffz * blockIdx.z + (size_t)rowg * ldc + colg;
        if (OUTF32) ((float*)C)[idx] = v;
        else ((_Float16*)C)[idx] = (_Float16)v;
      }
    }
}

// ---------------- G gemm, split-K-4: z = sp*4 + h, 256 blocks -------------
__launch_bounds__(256, 3)
__global__ void gemm_g_kernel(const _Float16* __restrict__ xb, const _Float16* __restrict__ WQKT,
                              float* __restrict__ gpart) {
  __shared__ __align__(16) _Float16 As[8192];
  __shared__ __align__(16) _Float16 Bs[8192];
  int tid = threadIdx.x;
  int z = blockIdx.z, sp = z >> 2, h = z & 3;
  const _Float16* Ab = xb + sp * 256 + (size_t)(blockIdx.y * 128) * 1024;
  const _Float16* Bb = WQKT + (size_t)h * 1048576 + sp * 256 + (size_t)(blockIdx.x * 128) * 1024;
  floatx4 acc[4][4];
  floatx4 zero = {0.f, 0.f, 0.f, 0.f};
#pragma unroll
  for (int a = 0; a < 4; a++)
#pragma unroll
    for (int b = 0; b < 4; b++) acc[a][b] = zero;
  gemm_core(Ab, 1024, Bb, 1024, 8, As, Bs, tid, acc);
  int lane = tid & 63, w = tid >> 6;
  int l15 = lane & 15, quad = lane >> 4;
  int wm = (w >> 1) * 64, wn = (w & 1) * 64;
#pragma unroll
  for (int mi = 0; mi < 4; mi++)
#pragma unroll
    for (int ni = 0; ni < 4; ni++) {
      int col = blockIdx.x * 128 + wn + ni * 16 + l15;
#pragma unroll
      for (int r = 0; r < 4; r++) {
        int row = blockIdx.y * 128 + wm + mi * 16 + quad * 4 + r;
        gpart[(size_t)z * 262144 + (size_t)row * 1024 + col] = acc[mi][ni][r];
      }
    }
}

// ---------------- reduce_g: 4 sp-partials + bqk -> G f16 ------------------
__global__ void reduce_g_kernel(const float* __restrict__ gpart, const float* __restrict__ bqk,
                                _Float16* __restrict__ G) {
  size_t e4 = ((size_t)blockIdx.x * 256 + threadIdx.x) * 4;   // 1024 blocks
  int h = (int)(e4 >> 18);
  size_t rem = e4 & 262143;
  int d = (int)(e4 & 1023);
  float4 s = *(const float4*)&bqk[h * 1024 + d];
#pragma unroll
  for (int sp = 0; sp < 4; sp++) {
    float4 p = *(const float4*)&gpart[(size_t)(sp * 4 + h) * 262144 + rem];
    s.x += p.x; s.y += p.y; s.z += p.z; s.w += p.w;
  }
  half4v o = {(_Float16)s.x, (_Float16)s.y, (_Float16)s.z, (_Float16)s.w};
  *(half4v*)&G[e4] = o;
}

// ---------------- wpack (unchanged, R9 core) ----------------
__launch_bounds__(256, 3)
__global__ void wpack_kernel(const _Float16* __restrict__ WoT, const _Float16* __restrict__ Wv16,
                             const _Float16* __restrict__ Wk16, const _Float16* __restrict__ Wq16,
                             const float* __restrict__ bv, const float* __restrict__ bq,
                             _Float16* __restrict__ WVOT, _Float16* __restrict__ WQKT,
                             float* __restrict__ bvwo, float* __restrict__ bqk) {
  __shared__ __align__(16) _Float16 As[8192];
  __shared__ __align__(16) _Float16 Bs[8192];
  int bid = blockIdx.x, tid = threadIdx.x;
  if (bid < 512) {
    bool isQK = bid >= 256;
    int g = bid & 255;
    int x = g & 7, y = (g >> 3) & 7, z = g >> 6;
    const _Float16* A = isQK ? Wk16 : WoT;
    const _Float16* B = isQK ? Wq16 : Wv16;
    const _Float16* Ab = A + 256 * z + (size_t)(y * 128) * 1024;
    const _Float16* Bb = B + 256 * z + (size_t)(x * 128) * 1024;
    floatx4 acc[4][4];
    floatx4 zero = {0.f, 0.f, 0.f, 0.f};
#pragma unroll
    for (int a = 0; a < 4; a++)
#pragma unroll
      for (int b = 0; b < 4; b++) acc[a][b] = zero;
    gemm_core(Ab, 1024, Bb, 1024, 8, As, Bs, tid, acc);
    float scale = isQK ? 0.0625f : 1.0f;
    _Float16* C = isQK ? WQKT : WVOT;
    size_t ldc = isQK ? 1024 : 4096;
    size_t zoff = isQK ? (size_t)1048576 * z : (size_t)1024 * z;
    int lane = tid & 63, w = tid >> 6;
    int l15 = lane & 15, quad = lane >> 4;
    int wm = (w >> 1) * 64, wn = (w & 1) * 64;
#pragma unroll
    for (int mi = 0; mi < 4; mi++)
#pragma unroll
      for (int ni = 0; ni < 4; ni++) {
        int col = x * 128 + wn + ni * 16 + l15;
#pragma unroll
        for (int r = 0; r < 4; r++) {
          int row = y * 128 + wm + mi * 16 + quad * 4 + r;
          C[zoff + (size_t)row * ldc + col] = (_Float16)(acc[mi][ni][r] * scale);
        }
      }
  } else if (bid < 516) {
    int j = (bid - 512) * 256 + tid;
    const half8* row = (const half8*)(WoT + (size_t)j * 1024);
    float a = 0.f;
    for (int c = 0; c < 128; c++) {
      half8 w8 = row[c];
#pragma unroll
      for (int e = 0; e < 8; e++) a += bv[c * 8 + e] * (float)w8[e];
    }
    bvwo[j] = a;
  } else {
    int idx = (bid - 516) * 256 + tid;
    int h = idx >> 10, f = idx & 1023;
    const _Float16* row = Wk16 + (size_t)f * 1024 + h * 256;
    float a = 0.f;
    for (int n = 0; n < 256; n++) a += bq[h * 256 + n] * (float)row[n];
    bqk[idx] = a * 0.0625f;
  }
}

// ---------------- S gemm: 256^2 core + exp epilogue + Zframe (R17) --------
__launch_bounds__(512, 2)
__global__ void gemm256_s_kernel(const _Float16* __restrict__ G, const _Float16* __restrict__ histb,
                                 _Float16* __restrict__ Eout, float* __restrict__ zframe) {
  __shared__ __align__(16) _Float16 SM[65536];
  _Float16* As = SM;
  _Float16* Bs = SM + 32768;
  int bid = blockIdx.x, tid = threadIdx.x;
  int h = bid >> 6, nt = bid & 63;
  const _Float16* Ab = G + (size_t)h * 262144;
  const _Float16* Bb = histb + (size_t)(nt * 256) * 1024;
  floatx4 acc[8][4];
  floatx4 zero = {0.f, 0.f, 0.f, 0.f};
#pragma unroll
  for (int a = 0; a < 8; a++)
#pragma unroll
    for (int b = 0; b < 4; b++) acc[a][b] = zero;
  gemm256_run(Ab, 1024, Bb, 1024, LinOff{}, As, Bs, tid, acc);
  int lane = tid & 63, w = tid >> 6;
  int l15 = lane & 15, quad = lane >> 4;
  int wr = w >> 2, wc = w & 3;
  __syncthreads();
#pragma unroll
  for (int mh = 0; mh < 2; mh++)
#pragma unroll
    for (int mi = 0; mi < 4; mi++)
#pragma unroll
      for (int ni = 0; ni < 4; ni++) {
        int col = wc * 64 + ni * 16 + l15;
#pragma unroll
        for (int r = 0; r < 4; r++) {
          int row = wr * 128 + mh * 64 + mi * 16 + quad * 4 + r;
          int colsw = col ^ (((row >> 2) & 3) << 3);
          SM[row * 256 + colsw] = (_Float16)__expf(acc[mh * 4 + mi][ni][r]);
        }
      }
  __syncthreads();
  int c32 = lane & 31, hs = lane >> 5;
#pragma unroll
  for (int it = 0; it < 16; it++) {
    int row = w * 32 + it * 2 + hs;
    int cs = (c32 * 8) ^ (((row >> 2) & 3) << 3);
    half8 v = *(const half8*)&SM[row * 256 + cs];
    float s = 0.f;
#pragma unroll
    for (int j = 0; j < 8; j++) s += (float)v[j];
#pragma unroll
    for (int off = 1; off <= 16; off <<= 1) s += __shfl_xor(s, off, 64);
    *(half8*)&Eout[(size_t)h * 4194304 + (size_t)row * TALL + nt * 256 + c32 * 8] = v;
    if (c32 == 0) zframe[(size_t)(h * 256 + row) * 64 + nt] = s;
  }
}

// ---------------- PH gemm (257 blocks: 256 GEMM + 1 csoftmax) -------------
// zframe now lives in OFF_PHR (no chunk overlap) -> block 256 race-free.
__launch_bounds__(512, 2)
__global__ void gemm256_ph_kernel(const _Float16* __restrict__ E, const _Float16* __restrict__ histT,
                                  const float* __restrict__ zframe, const float* __restrict__ dil_w,
                                  float* __restrict__ w4, char* __restrict__ ws) {
  __shared__ __align__(16) _Float16 SM[65536];
  int bid = blockIdx.x, tid = threadIdx.x;
  if (bid == 256) {                        // csoftmax: zframe -> w4
    float w0 = dil_w[0], w1 = dil_w[1], w2 = dil_w[2], w3 = dil_w[3];
    float wmx = fmaxf(fmaxf(w0, w1), fmaxf(w2, w3));
    float e0 = __expf(w0 - wmx), e1 = __expf(w1 - wmx), e2 = __expf(w2 - wmx), e3 = __expf(w3 - wmx);
    float wsum = e0 + e1 + e2 + e3;
#pragma unroll
    for (int i = 0; i < 2; i++) {
      int row = i * 512 + tid;
      const float* z = zframe + (size_t)row * 64;
      float z1 = 0.f, z4 = 0.f, z8 = 0.f, z16 = 0.f;
#pragma unroll
      for (int f = 0; f < 64; f++) {
        float v = z[f];
        z1 += v;
        if (!(f & 3))  z4 += v;
        if (!(f & 7))  z8 += v;
        if (!(f & 15)) z16 += v;
      }
      float b0 = (e0 / wsum) / z1 * 256.0f;
      float b1 = (e1 / wsum) / z4 * 256.0f;
      float b2 = (e2 / wsum) / z8 * 256.0f;
      float b3 = (e3 / wsum) / z16 * 256.0f;
      float* wr = w4 + (size_t)row * 4;
      wr[0] = b0;
      wr[1] = b0 + b1;
      wr[2] = b0 + b1 + b2;
      wr[3] = b0 + b1 + b2 + b3;
    }
    return;
  }
  _Float16* As = SM;
  _Float16* Bs = SM + 32768;
  int xcd = bid & 7, slot = bid >> 3;
  int g = xcd + 8 * (slot >> 4);
  int member = slot & 15;
  int h = member >> 2, nt = member & 3;
  const _Float16* A = E + (size_t)h * 4194304;
  const _Float16* B = histT + (size_t)(nt * 256) * TALL;
  floatx4 acc[8][4];
  floatx4 zero = {0.f, 0.f, 0.f, 0.f};
#pragma unroll
  for (int a = 0; a < 8; a++)
#pragma unroll
    for (int b = 0; b < 4; b++) acc[a][b] = zero;
  gemm256_run(A, TALL, B, TALL, ClsOff{g}, As, Bs, tid, acc);
  int lane = tid & 63, w = tid >> 6;
  int l15 = lane & 15, quad = lane >> 4;
  int wr = w >> 2, wc = w & 3;
  __syncthreads();
#pragma unroll
  for (int mh = 0; mh < 2; mh++)
#pragma unroll
    for (int mi = 0; mi < 4; mi++)
#pragma unroll
      for (int ni = 0; ni < 4; ni++) {
        int col = wc * 64 + ni * 16 + l15;
#pragma unroll
        for (int r = 0; r < 4; r++) {
          int row = wr * 128 + mh * 64 + mi * 16 + quad * 4 + r;
          int colsw = col ^ (((row >> 2) & 3) << 3);
          SM[row * 256 + colsw] = (_Float16)acc[mh * 4 + mi][ni][r];
        }
      }
  __syncthreads();
  _Float16* chunk = (_Float16*)(ws + chunk16_off(g));
  int c32 = lane & 31, hs = lane >> 5;
  int colbase = h * 1024 + nt * 256;
#pragma unroll
  for (int it = 0; it < 16; it++) {
    int row = w * 32 + it * 2 + hs;
    int cs = (c32 * 8) ^ (((row >> 2) & 3) << 3);
    half8 v = *(const half8*)&SM[row * 256 + cs];
    *(half8*)&chunk[(size_t)row * 4096 + colbase + c32 * 8] = v;
  }
}

// ---------------- reduce: 4 class sums x per-(h,q) weights -> PHred -------
__global__ void reduce_ph_kernel(const char* __restrict__ ws, const float* __restrict__ w4,
                                 _Float16* __restrict__ PHred) {
  size_t e8 = ((size_t)blockIdx.x * 256 + threadIdx.x) * 8;
  int q = (int)(e8 >> 12);
  int h = (int)((e8 >> 10) & 3);
  const float* wr = w4 + (size_t)(h * 256 + q) * 4;
  float sA[8] = {0,0,0,0,0,0,0,0}, sB[8] = {0,0,0,0,0,0,0,0};
  float sC[8] = {0,0,0,0,0,0,0,0}, sD[8] = {0,0,0,0,0,0,0,0};
#pragma unroll
  for (int g = 0; g < 12; g++) {
    const _Float16* p = (const _Float16*)(ws + chunk16_off(g));
    half8 v = *(const half8*)&p[e8];
#pragma unroll
    for (int j = 0; j < 8; j++) sA[j] += (float)v[j];
  }
#pragma unroll
  for (int g = 12; g < 14; g++) {
    const _Float16* p = (const _Float16*)(ws + chunk16_off(g));
    half8 v = *(const half8*)&p[e8];
#pragma unroll
    for (int j = 0; j < 8; j++) sB[j] += (float)v[j];
  }
  {
    const _Float16* p = (const _Float16*)(ws + chunk16_off(14));
    half8 v = *(const half8*)&p[e8];
#pragma unroll
    for (int j = 0; j < 8; j++) sC[j] += (float)v[j];
  }
  {
    const _Float16* p = (const _Float16*)(ws + chunk16_off(15));
    half8 v = *(const half8*)&p[e8];
#pragma unroll
    for (int j = 0; j < 8; j++) sD[j] += (float)v[j];
  }
  float wA = wr[0], wB = wr[1], wC = wr[2], wD = wr[3];
  half8 o;
#pragma unroll
  for (int j = 0; j < 8; j++)
    o[j] = (_Float16)(wA * sA[j] + wB * sB[j] + wC * sC[j] + wD * sD[j]);
  *(half8*)&PHred[e8] = o;
}

// ---------------- FO 16-way reduce + bo + bv@Wo + residual + layernorm ----
__global__ void ln_kernel(const float* __restrict__ x, const float* __restrict__ part2,
                          const float* __restrict__ bo, const float* __restrict__ bvwo,
                          const float* __restrict__ gamma, const float* __restrict__ beta,
                          float* __restrict__ out) {
  int b = blockIdx.x, t = threadIdx.x;
  __shared__ float red[8];
  float y[4];
  float sum = 0.f, sq = 0.f;
#pragma unroll
  for (int i = 0; i < 4; i++) {
    int j = t + i * 256;
    float v = x[(size_t)b * 1024 + j] + bo[j] + bvwo[j];
#pragma unroll
    for (int z = 0; z < 16; z++) v += part2[(size_t)z * 262144 + (size_t)b * 1024 + j];
    y[i] = v;
    sum += v;
    sq += v * v;
  }
#pragma unroll
  for (int off = 1; off < 64; off <<= 1) {
    sum += __shfl_xor(sum, off, 64);
    sq += __shfl_xor(sq, off, 64);
  }
  int w = t >> 6, lane = t & 63;
  if (lane == 0) { red[w] = sum; red[4 + w] = sq; }
  __syncthreads();
  sum = red[0] + red[1] + red[2] + red[3];
  sq = red[4] + red[5] + red[6] + red[7];
  float mu = sum * (1.f / 1024.f);
  float var = sq * (1.f / 1024.f) - mu * mu;
  float inv = rsqrtf(var + 1e-5f);
#pragma unroll
  for (int i = 0; i < 4; i++) {
    int j = t + i * 256;
    out[(size_t)b * 1024 + j] = (y[i] - mu) * inv * gamma[j] + beta[j];
  }
}

// ---------------- host launch ----------------
extern "C" void kernel_launch(void* const* d_in, const int* in_sizes, int n_in,
                              void* d_out, int out_size, void* d_ws, size_t ws_size,
                              hipStream_t stream) {
  const float* x     = (const float*)d_in[0];
  const float* hist  = (const float*)d_in[1];
  const float* Wq    = (const float*)d_in[2];
  const float* bq    = (const float*)d_in[3];
  const float* Wk    = (const float*)d_in[4];
  // bk (d_in[5]) dropped exactly: softmax shift invariance.
  const float* Wv    = (const float*)d_in[6];
  const float* bv    = (const float*)d_in[7];
  const float* Wo    = (const float*)d_in[8];
  const float* bo    = (const float*)d_in[9];
  const float* dil_w = (const float*)d_in[10];
  const float* gamma = (const float*)d_in[11];
  const float* beta  = (const float*)d_in[12];
  char* ws = (char*)d_ws;

  _Float16* WoT   = (_Float16*)(ws + OFF_WOT);
  _Float16* Wv16  = (_Float16*)(ws + OFF_WV16);
  _Float16* Wk16  = (_Float16*)(ws + OFF_WK16);
  _Float16* Wq16  = (_Float16*)(ws + OFF_WQ16);
  _Float16* xb    = (_Float16*)(ws + OFF_XB);
  _Float16* G     = (_Float16*)(ws + OFF_G);
  _Float16* WVOT  = (_Float16*)(ws + OFF_WVOT);
  _Float16* WQKT  = (_Float16*)(ws + OFF_WQKT);
  float* bvwo     = (float*)(ws + OFF_BVWO);
  float* bqk      = (float*)(ws + OFF_BQK);
  _Float16* PHred = (_Float16*)(ws + OFF_PHR);
  float* oppart   = (float*)(ws + OFF_OPP);    // 16 MB (OPP + dead histb head)
  _Float16* histb = (_Float16*)(ws + OFF_HB);
  _Float16* histT = (_Float16*)(ws + OFF_HT);
  _Float16* Eb    = (_Float16*)(ws + OFF_S);
  float* gpart    = (float*)(ws + OFF_S);      // 16 MB; dead before S writes Eb
  float* zframe   = (float*)(ws + OFF_PHR);    // 256 KB in PHR region (no chunk overlap;
                                               // PHred overwrites it only at reduce_ph)
  float* w4       = (float*)(ws + OFF_G);      // 16 KB; G dead after S

  // 1) prep
  prep_kernel<<<dim3(8448), 256, 0, stream>>>(Wo, Wv, Wk, Wq, x, hist,
                                              WoT, Wv16, Wk16, Wq16, xb, histb, histT);
  // 2) wpack
  wpack_kernel<<<dim3(532), 256, 0, stream>>>(WoT, Wv16, Wk16, Wq16, bv, bq,
                                              WVOT, WQKT, bvwo, bqk);
  // 3) G split-K-4 partials (256 blocks) + reduce
  gemm_g_kernel<<<dim3(8, 2, 16), 256, 0, stream>>>(xb, WQKT, gpart);
  reduce_g_kernel<<<dim3(1024), 256, 0, stream>>>(gpart, bqk, G);
  // 4) E = exp(G @ hist^T) + Zframe
  gemm256_s_kernel<<<dim3(256), 512, 0, stream>>>(G, histb, Eb, zframe);
  // 5) PH class-partials (+ csoftmax block 256; zframe in PHR, race-free)
  gemm256_ph_kernel<<<dim3(257), 512, 0, stream>>>(Eb, histT, zframe, dil_w, w4, ws);
  // 6) reduce: class sums x w4 -> PHred
  reduce_ph_kernel<<<dim3(512), 256, 0, stream>>>(ws, w4, PHred);
  // 7) FO split-16 (256 blocks)
  gemm_f16_kernel<true><<<dim3(8, 2, 16), 256, 0, stream>>>(
      PHred, 4096, 256, WVOT, 4096, 256, 8, nullptr, 0, 1.0f / 256.0f,
      (void*)oppart, 1024, 262144);
  // 8) 16-way reduce + bo + bv@Wo + residual + layernorm
  ln_kernel<<<dim3(256), 256, 0, stream>>>(x, oppart, bo, bvwo, gamma, beta, (float*)d_out);
}

// Round 15
// 300.731 us; speedup vs baseline: 1.0575x; 1.0062x over previous
//
#include <hip/hip_runtime.h>

// TemporalDilatedAttention on gfx950 — round 21
// vs R20 (PASSED 302.6us, best): minimal-barrier 256^2 core. R17/R20's core
// ran 3 barriers/K-tile (96/kernel) at 1 block/CU where each barrier stalls
// the whole CU. Ledger re-derivation: the ENTRY barrier alone certifies both
// (a) all waves' stage-loads for buf t landed (each wave passes its own
// vmcnt first) and (b) all waves completed reads of buf t-1 (each wave's
// phase-2 lgkmcnt(0) of t-1 precedes its entry barrier in program order) —
// which is exactly the WAR cert the stage(t+3) writes into buf (t-1)&3
// need, since they issue after the entry barrier. The two intra-tile
// barriers only aligned MFMA clusters (measured null in R14) -> removed.
// 96 -> 32 barriers/kernel; per-phase lgkmcnt(0) tails kept (WAR anchor);
// MFMA order per accumulator unchanged -> numerics bit-identical.
// Everything else identical to R20 (G split-K-4, FO split-16, fused
// exp+Zframe, frame-class chunks, csoftmax in PH block 256).

#define DD    1024
#define TALL  16384

typedef _Float16 half8  __attribute__((ext_vector_type(8)));
typedef _Float16 half4v __attribute__((ext_vector_type(4)));
typedef float    floatx4 __attribute__((ext_vector_type(4)));
typedef unsigned int u32;

// ---------------- workspace layout (bytes), ~132.5 MB ----------------
static const size_t OFF_WOT  = 0;          // 2 MB  Wo^T f16
static const size_t OFF_WV16 = 2097152;    // 2 MB  Wv f16
static const size_t OFF_WK16 = 4194304;    // 2 MB  Wk f16
static const size_t OFF_WQ16 = 6291456;    // 2 MB  Wq f16
static const size_t OFF_XB   = 8388608;    // 0.5 MB x f16
static const size_t OFF_G    = 8912896;    // 2 MB  G f16; w4 table after S
static const size_t OFF_WVOT = 11010048;   // 8 MB  WVOT f16 (LIVE through FO)
static const size_t OFF_WQKT = 19398656;   // 8 MB  WQKT f16 (dead after G; chunks 4-7 here)
static const size_t OFF_BVWO = 27787264;   // 4 KB  bv@Wo f32
static const size_t OFF_BQK  = 27791360;   // 16 KB bqk f32
static const size_t OFF_PHR  = 27807744;   // 2 MB  zframe (S->PH), then PHred f16
static const size_t OFF_OPP  = 29904896;   // 16 MB FO partials f32 (spills into dead histb head)
static const size_t OFF_HB   = 38293504;   // 32 MB histb (dead after S)
static const size_t OFF_HT   = 71848960;   // 32 MB hist^T f16 [feat][t]
static const size_t OFF_S    = 105403392;  // 32 MB: G split-K partials (16MB) then E f16

// PH f16 partial chunks: 16 x 2 MB over regions dead during launches 5-6.
__device__ __forceinline__ size_t chunk16_off(int g) {
  if (g < 4)  return (size_t)g * 2097152;
  if (g < 8)  return 19398656 + (size_t)(g - 4) * 2097152;
  if (g < 12) return 29904896 + (size_t)(g - 8) * 2097152;
  return 38293504 + (size_t)(g - 12) * 2097152;
}

// Frame-class chunk map: chunk g, sub-frame j (0..3) -> frame index.
__device__ __forceinline__ int frame_of(int g, int j) {
  if (g < 12) { int m = g * 4 + j; return m + m / 3 + 1; }
  if (g < 14) return 4 + 8 * ((g - 12) * 4 + j);
  if (g == 14) return 8 + 16 * j;
  return 16 * j;
}
__device__ __forceinline__ size_t foff(int g, int t) {
  return (size_t)frame_of(g, t >> 3) * 512 + (size_t)(t & 7) * 64;
}

// ---------------- async global->LDS, 16B per lane ----------------
__device__ __forceinline__ void gl_lds16(const void* g, void* l) {
  __builtin_amdgcn_global_load_lds((const __attribute__((address_space(1))) u32*)g,
                                   (__attribute__((address_space(3))) u32*)l, 16, 0, 0);
}

// ---------------- prep (unchanged) ----------------
__global__ void prep_kernel(const float* __restrict__ Wo, const float* __restrict__ Wv,
                            const float* __restrict__ Wk, const float* __restrict__ Wq,
                            const float* __restrict__ x, const float* __restrict__ hist,
                            _Float16* __restrict__ WoT, _Float16* __restrict__ Wv16,
                            _Float16* __restrict__ Wk16, _Float16* __restrict__ Wq16,
                            _Float16* __restrict__ xb, _Float16* __restrict__ histb,
                            _Float16* __restrict__ histT) {
  int bid = blockIdx.x, tid = threadIdx.x;
  if (bid < 1024) {                        // Wo transpose+cvt
    int k0 = (bid & 31) * 32, n0 = (bid >> 5) * 32;
    __shared__ float t32[32][33];
    int tx = tid & 31, ty = tid >> 5;
#pragma unroll
    for (int i = 0; i < 4; i++) {
      int r = ty + i * 8;
      t32[r][tx] = Wo[(size_t)(k0 + r) * DD + n0 + tx];
    }
    __syncthreads();
#pragma unroll
    for (int i = 0; i < 4; i++) {
      int r = ty + i * 8;
      WoT[(size_t)(n0 + r) * DD + k0 + tx] = (_Float16)t32[tx][r];
    }
  } else if (bid < 4352) {                 // plain cvt
    const float* src; _Float16* dst; size_t i;
    if (bid < 2048)      { src = Wv; dst = Wv16; i = (size_t)(bid - 1024) * 256 + tid; }
    else if (bid < 3072) { src = Wk; dst = Wk16; i = (size_t)(bid - 2048) * 256 + tid; }
    else if (bid < 4096) { src = Wq; dst = Wq16; i = (size_t)(bid - 3072) * 256 + tid; }
    else                 { src = x;  dst = xb;   i = (size_t)(bid - 4096) * 256 + tid; }
    float4 v = ((const float4*)src)[i];
    half4v h = {(_Float16)v.x, (_Float16)v.y, (_Float16)v.z, (_Float16)v.w};
    *(half4v*)(dst + 4 * i) = h;
  } else {                                 // hist dual write
    int tb = bid - 4352;
    int t0 = (tb & 255) * 64, f0 = (tb >> 8) * 64;
    __shared__ _Float16 lt[64][72];
    int r = tid >> 2, c0 = (tid & 3) * 16;
    half8 s0, s1;
#pragma unroll
    for (int i = 0; i < 4; i++) {
      float4 v = *(const float4*)&hist[(size_t)(t0 + r) * 1024 + f0 + c0 + i * 4];
      half4v h = {(_Float16)v.x, (_Float16)v.y, (_Float16)v.z, (_Float16)v.w};
      *(half4v*)&lt[r][c0 + i * 4] = h;
      if (i < 2) { s0[i*4]=h[0]; s0[i*4+1]=h[1]; s0[i*4+2]=h[2]; s0[i*4+3]=h[3]; }
      else { s1[(i-2)*4]=h[0]; s1[(i-2)*4+1]=h[1]; s1[(i-2)*4+2]=h[2]; s1[(i-2)*4+3]=h[3]; }
    }
    *(half8*)&histb[(size_t)(t0 + r) * 1024 + f0 + c0] = s0;
    *(half8*)&histb[(size_t)(t0 + r) * 1024 + f0 + c0 + 8] = s1;
    __syncthreads();
    int fr = tid >> 2, tc0 = (tid & 3) * 16;
    half8 o0, o1;
#pragma unroll
    for (int j = 0; j < 8; j++) { o0[j] = lt[tc0 + j][fr]; o1[j] = lt[tc0 + 8 + j][fr]; }
    *(half8*)&histT[(size_t)(f0 + fr) * TALL + t0 + tc0] = o0;
    *(half8*)&histT[(size_t)(f0 + fr) * TALL + t0 + tc0 + 8] = o1;
  }
}

// ---------------- R9 128x128 core (wpack/G/FO) ----------------------------
__device__ __forceinline__ void gemm_core(const _Float16* __restrict__ A, size_t lda,
                                          const _Float16* __restrict__ B, size_t ldb,
                                          int kIters, _Float16* As, _Float16* Bs,
                                          int tid, floatx4 acc[4][4]) {
  int lane = tid & 63, w = tid >> 6;
  int l15 = lane & 15, quad = lane >> 4;
  int wm = (w >> 1) * 64, wn = (w & 1) * 64;
  int swz = ((tid & 3) ^ ((tid >> 3) & 3)) * 8;
  int pch = (quad ^ ((l15 >> 1) & 3)) * 8;
  const char* gA0 = (const char*)(A + (size_t)(tid >> 2) * lda + swz);
  const char* gA1 = (const char*)(A + ((size_t)(tid >> 2) + 64) * lda + swz);
  const char* gB0 = (const char*)(B + (size_t)(tid >> 2) * ldb + swz);
  const char* gB1 = (const char*)(B + ((size_t)(tid >> 2) + 64) * ldb + swz);
  _Float16* lA = As + w * 512;
  _Float16* lB = Bs + w * 512;
#define GC_STAGE(buf, k)                                    \
  do {                                                      \
    size_t off_ = (size_t)(k) * 64;                         \
    gl_lds16(gA0 + off_, lA + (buf) * 4096);                \
    gl_lds16(gA1 + off_, lA + (buf) * 4096 + 2048);         \
    gl_lds16(gB0 + off_, lB + (buf) * 4096);                \
    gl_lds16(gB1 + off_, lB + (buf) * 4096 + 2048);         \
  } while (0)
#define GC_STEP(buf, k)                                                       \
  do {                                                                        \
    if ((k) + 1 < kIters) asm volatile("s_waitcnt vmcnt(4)" ::: "memory");    \
    else                  asm volatile("s_waitcnt vmcnt(0)" ::: "memory");    \
    asm volatile("s_barrier" ::: "memory");                                   \
    const _Float16* Ac_ = As + (buf) * 4096;                                  \
    const _Float16* Bc_ = Bs + (buf) * 4096;                                  \
    half8 a_[4];                                                              \
    _Pragma("unroll")                                                         \
    for (int mi = 0; mi < 4; mi++)                                            \
      a_[mi] = *(const half8*)&Ac_[(wm + mi * 16 + l15) * 32 + pch];          \
    _Pragma("unroll")                                                         \
    for (int ni = 0; ni < 4; ni++) {                                          \
      half8 b8_ = *(const half8*)&Bc_[(wn + ni * 16 + l15) * 32 + pch];       \
      _Pragma("unroll")                                                       \
      for (int mi = 0; mi < 4; mi++)                                          \
        acc[mi][ni] = __builtin_amdgcn_mfma_f32_16x16x32_f16(a_[mi], b8_,     \
                                                             acc[mi][ni], 0, 0, 0); \
    }                                                                         \
    asm volatile("s_waitcnt lgkmcnt(0)" ::: "memory");                        \
    asm volatile("s_barrier" ::: "memory");                                   \
    if ((k) + 2 < kIters) GC_STAGE(buf, (k) + 2);                             \
  } while (0)
  GC_STAGE(0, 0);
  GC_STAGE(1, 1);
  for (int kk = 0; kk < kIters; kk += 2) {
    GC_STEP(0, kk);
    GC_STEP(1, kk + 1);
  }
#undef GC_STEP
#undef GC_STAGE
}

// ---------------- 256x256 8-wave BK=32 minimal-barrier core ---------------
// ONE barrier per tile (entry). Ledger: entry barrier t certifies (a) all
// waves' stage-loads for buf t landed (each wave's vmcnt precedes it) and
// (b) all waves' reads of buf t-1 completed (each wave's phase-2 lgkmcnt(0)
// of t-1 precedes its entry barrier t in program order). PSTA/PSTB(t+3)
// overwrite buf (t-1)&3 and issue AFTER entry barrier t -> WAR-safe.
// Per-phase lgkmcnt(0) tails kept as the program-order anchor for (b).
template <typename OFF>
__device__ __forceinline__ void gemm256_run(const _Float16* __restrict__ A, size_t lda,
                                            const _Float16* __restrict__ B, size_t ldb,
                                            OFF off, _Float16* As, _Float16* Bs,
                                            int tid, floatx4 acc[8][4]) {
  int lane = tid & 63, w = tid >> 6;
  int l15 = lane & 15, quad = lane >> 4;
  int wr = w >> 2, wc = w & 3;
  int pch = (quad ^ ((l15 >> 1) & 3)) * 8;
  int srow = tid >> 2;
  int schunk = (tid & 3) ^ ((tid >> 3) & 3);
  const char* gA0 = (const char*)(A + (size_t)srow * lda + schunk * 8);
  const char* gA1 = (const char*)(A + (size_t)(srow + 128) * lda + schunk * 8);
  const char* gB0 = (const char*)(B + (size_t)srow * ldb + schunk * 8);
  const char* gB1 = (const char*)(B + (size_t)(srow + 128) * ldb + schunk * 8);
  _Float16* lA = As + w * 512;
  _Float16* lB = Bs + w * 512;
#define PSTA(buf, t)                                          \
  do { size_t o_ = off(t);                                    \
    gl_lds16(gA0 + o_, lA + (buf) * 8192);                    \
    gl_lds16(gA1 + o_, lA + (buf) * 8192 + 4096);             \
  } while (0)
#define PSTB(buf, t)                                          \
  do { size_t o_ = off(t);                                    \
    gl_lds16(gB0 + o_, lB + (buf) * 8192);                    \
    gl_lds16(gB1 + o_, lB + (buf) * 8192 + 4096);             \
  } while (0)
  PSTA(0, 0); PSTB(0, 0);
  PSTA(1, 1); PSTB(1, 1);
  PSTA(2, 2); PSTB(2, 2);
  for (int t = 0; t < 32; ++t) {
    int buf = t & 3;
    if (t + 2 < 32)      asm volatile("s_waitcnt vmcnt(8)" ::: "memory");
    else if (t + 1 < 32) asm volatile("s_waitcnt vmcnt(4)" ::: "memory");
    else                 asm volatile("s_waitcnt vmcnt(0)" ::: "memory");
    asm volatile("s_barrier" ::: "memory");
    const _Float16* Ac = As + buf * 8192;
    const _Float16* Bc = Bs + buf * 8192;
    half8 b8[4], a8[4];
#pragma unroll
    for (int ni = 0; ni < 4; ni++)
      b8[ni] = *(const half8*)&Bc[(wc * 64 + ni * 16 + l15) * 32 + pch];
#pragma unroll
    for (int mi = 0; mi < 4; mi++)
      a8[mi] = *(const half8*)&Ac[(wr * 128 + mi * 16 + l15) * 32 + pch];
    if (t + 3 < 32) PSTA((t + 3) & 3, t + 3);
    asm volatile("s_waitcnt lgkmcnt(0)" ::: "memory");
    __builtin_amdgcn_s_setprio(1);
#pragma unroll
    for (int mi = 0; mi < 4; mi++)
#pragma unroll
      for (int ni = 0; ni < 4; ni++)
        acc[mi][ni] = __builtin_amdgcn_mfma_f32_16x16x32_f16(a8[mi], b8[ni], acc[mi][ni], 0, 0, 0);
    __builtin_amdgcn_s_setprio(0);
#pragma unroll
    for (int mi = 0; mi < 4; mi++)
      a8[mi] = *(const half8*)&Ac[(wr * 128 + 64 + mi * 16 + l15) * 32 + pch];
    if (t + 3 < 32) PSTB((t + 3) & 3, t + 3);
    asm volatile("s_waitcnt lgkmcnt(0)" ::: "memory");
    __builtin_amdgcn_s_setprio(1);
#pragma unroll
    for (int mi = 0; mi < 4; mi++)
#pragma unroll
      for (int ni = 0; ni < 4; ni++)
        acc[4 + mi][ni] = __builtin_amdgcn_mfma_f32_16x16x32_f16(a8[mi], b8[ni], acc[4 + mi][ni], 0, 0, 0);
    __builtin_amdgcn_s_setprio(0);
  }
#undef PSTA
#undef PSTB
}

struct LinOff { __device__ __forceinline__ size_t operator()(int t) const { return (size_t)t * 64; } };
struct ClsOff { int g; __device__ __forceinline__ size_t operator()(int t) const { return foff(g, t); } };

// ---------------- generic single-B GEMM (R9 core) ----------------
template <bool OUTF32>
__launch_bounds__(256, 3)
__global__ void gemm_f16_kernel(const _Float16* __restrict__ A, size_t lda, size_t aoffz,
                                const _Float16* __restrict__ B, size_t ldb, size_t boffz,
                                int kIters, const float* __restrict__ bias, size_t biasoffz,
                                float scale, void* __restrict__ C, size_t ldc, size_t coffz) {
  __shared__ __align__(16) _Float16 As[8192];
  __shared__ __align__(16) _Float16 Bs[8192];
  int tid = threadIdx.x;
  const _Float16* Ab = A + aoffz * blockIdx.z + (size_t)(blockIdx.y * 128) * lda;
  const _Float16* Bb = B + boffz * blockIdx.z + (size_t)(blockIdx.x * 128) * ldb;
  floatx4 acc[4][4];
  floatx4 zero = {0.f, 0.f, 0.f, 0.f};
#pragma unroll
  for (int a = 0; a < 4; a++)
#pragma unroll
    for (int b = 0; b < 4; b++) acc[a][b] = zero;
  gemm_core(Ab, lda, Bb, ldb, kIters, As, Bs, tid, acc);
  int lane = tid & 63, w = tid >> 6;
  int l15 = lane & 15, quad = lane >> 4;
  int wm = (w >> 1) * 64, wn = (w & 1) * 64;
#pragma unroll
  for (int mi = 0; mi < 4; mi++)
#pragma unroll
    for (int ni = 0; ni < 4; ni++) {
      int colg = blockIdx.x * 128 + wn + ni * 16 + l15;
      float bv = bias ? bias[biasoffz * blockIdx.z + colg] : 0.f;
#pragma unroll
      for (int r = 0; r < 4; r++) {
        int rowg = blockIdx.y * 128 + wm + mi * 16 + quad * 4 + r;
        float v = (acc[mi][ni][r] + bv) * scale;
        size_t idx = coffz * blockIdx.z + (size_t)rowg * ldc + colg;
        if (OUTF32) ((float*)C)[idx] = v;
        else ((_Float16*)C)[idx] = (_Float16)v;
      }
    }
}

// ---------------- G gemm, split-K-4: z = sp*4 + h, 256 blocks -------------
__launch_bounds__(256, 3)
__global__ void gemm_g_kernel(const _Float16* __restrict__ xb, const _Float16* __restrict__ WQKT,
                              float* __restrict__ gpart) {
  __shared__ __align__(16) _Float16 As[8192];
  __shared__ __align__(16) _Float16 Bs[8192];
  int tid = threadIdx.x;
  int z = blockIdx.z, sp = z >> 2, h = z & 3;
  const _Float16* Ab = xb + sp * 256 + (size_t)(blockIdx.y * 128) * 1024;
  const _Float16* Bb = WQKT + (size_t)h * 1048576 + sp * 256 + (size_t)(blockIdx.x * 128) * 1024;
  floatx4 acc[4][4];
  floatx4 zero = {0.f, 0.f, 0.f, 0.f};
#pragma unroll
  for (int a = 0; a < 4; a++)
#pragma unroll
    for (int b = 0; b < 4; b++) acc[a][b] = zero;
  gemm_core(Ab, 1024, Bb, 1024, 8, As, Bs, tid, acc);
  int lane = tid & 63, w = tid >> 6;
  int l15 = lane & 15, quad = lane >> 4;
  int wm = (w >> 1) * 64, wn = (w & 1) * 64;
#pragma unroll
  for (int mi = 0; mi < 4; mi++)
#pragma unroll
    for (int ni = 0; ni < 4; ni++) {
      int col = blockIdx.x * 128 + wn + ni * 16 + l15;
#pragma unroll
      for (int r = 0; r < 4; r++) {
        int row = blockIdx.y * 128 + wm + mi * 16 + quad * 4 + r;
        gpart[(size_t)z * 262144 + (size_t)row * 1024 + col] = acc[mi][ni][r];
      }
    }
}

// ---------------- reduce_g: 4 sp-partials + bqk -> G f16 ------------------
__global__ void reduce_g_kernel(const float* __restrict__ gpart, const float* __restrict__ bqk,
                                _Float16* __restrict__ G) {
  size_t e4 = ((size_t)blockIdx.x * 256 + threadIdx.x) * 4;   // 1024 blocks
  int h = (int)(e4 >> 18);
  size_t rem = e4 & 262143;
  int d = (int)(e4 & 1023);
  float4 s = *(const float4*)&bqk[h * 1024 + d];
#pragma unroll
  for (int sp = 0; sp < 4; sp++) {
    float4 p = *(const float4*)&gpart[(size_t)(sp * 4 + h) * 262144 + rem];
    s.x += p.x; s.y += p.y; s.z += p.z; s.w += p.w;
  }
  half4v o = {(_Float16)s.x, (_Float16)s.y, (_Float16)s.z, (_Float16)s.w};
  *(half4v*)&G[e4] = o;
}

// ---------------- wpack (unchanged, R9 core) ----------------
__launch_bounds__(256, 3)
__global__ void wpack_kernel(const _Float16* __restrict__ WoT, const _Float16* __restrict__ Wv16,
                             const _Float16* __restrict__ Wk16, const _Float16* __restrict__ Wq16,
                             const float* __restrict__ bv, const float* __restrict__ bq,
                             _Float16* __restrict__ WVOT, _Float16* __restrict__ WQKT,
                             float* __restrict__ bvwo, float* __restrict__ bqk) {
  __shared__ __align__(16) _Float16 As[8192];
  __shared__ __align__(16) _Float16 Bs[8192];
  int bid = blockIdx.x, tid = threadIdx.x;
  if (bid < 512) {
    bool isQK = bid >= 256;
    int g = bid & 255;
    int x = g & 7, y = (g >> 3) & 7, z = g >> 6;
    const _Float16* A = isQK ? Wk16 : WoT;
    const _Float16* B = isQK ? Wq16 : Wv16;
    const _Float16* Ab = A + 256 * z + (size_t)(y * 128) * 1024;
    const _Float16* Bb = B + 256 * z + (size_t)(x * 128) * 1024;
    floatx4 acc[4][4];
    floatx4 zero = {0.f, 0.f, 0.f, 0.f};
#pragma unroll
    for (int a = 0; a < 4; a++)
#pragma unroll
      for (int b = 0; b < 4; b++) acc[a][b] = zero;
    gemm_core(Ab, 1024, Bb, 1024, 8, As, Bs, tid, acc);
    float scale = isQK ? 0.0625f : 1.0f;
    _Float16* C = isQK ? WQKT : WVOT;
    size_t ldc = isQK ? 1024 : 4096;
    size_t zoff = isQK ? (size_t)1048576 * z : (size_t)1024 * z;
    int lane = tid & 63, w = tid >> 6;
    int l15 = lane & 15, quad = lane >> 4;
    int wm = (w >> 1) * 64, wn = (w & 1) * 64;
#pragma unroll
    for (int mi = 0; mi < 4; mi++)
#pragma unroll
      for (int ni = 0; ni < 4; ni++) {
        int col = x * 128 + wn + ni * 16 + l15;
#pragma unroll
        for (int r = 0; r < 4; r++) {
          int row = y * 128 + wm + mi * 16 + quad * 4 + r;
          C[zoff + (size_t)row * ldc + col] = (_Float16)(acc[mi][ni][r] * scale);
        }
      }
  } else if (bid < 516) {
    int j = (bid - 512) * 256 + tid;
    const half8* row = (const half8*)(WoT + (size_t)j * 1024);
    float a = 0.f;
    for (int c = 0; c < 128; c++) {
      half8 w8 = row[c];
#pragma unroll
      for (int e = 0; e < 8; e++) a += bv[c * 8 + e] * (float)w8[e];
    }
    bvwo[j] = a;
  } else {
    int idx = (bid - 516) * 256 + tid;
    int h = idx >> 10, f = idx & 1023;
    const _Float16* row = Wk16 + (size_t)f * 1024 + h * 256;
    float a = 0.f;
    for (int n = 0; n < 256; n++) a += bq[h * 256 + n] * (float)row[n];
    bqk[idx] = a * 0.0625f;
  }
}

// ---------------- S gemm: minimal-barrier core + exp epilogue + Zframe ----
__launch_bounds__(512, 2)
__global__ void gemm256_s_kernel(const _Float16* __restrict__ G, const _Float16* __restrict__ histb,
                                 _Float16* __restrict__ Eout, float* __restrict__ zframe) {
  __shared__ __align__(16) _Float16 SM[65536];
  _Float16* As = SM;
  _Float16* Bs = SM + 32768;
  int bid = blockIdx.x, tid = threadIdx.x;
  int h = bid >> 6, nt = bid & 63;
  const _Float16* Ab = G + (size_t)h * 262144;
  const _Float16* Bb = histb + (size_t)(nt * 256) * 1024;
  floatx4 acc[8][4];
  floatx4 zero = {0.f, 0.f, 0.f, 0.f};
#pragma unroll
  for (int a = 0; a < 8; a++)
#pragma unroll
    for (int b = 0; b < 4; b++) acc[a][b] = zero;
  gemm256_run(Ab, 1024, Bb, 1024, LinOff{}, As, Bs, tid, acc);
  int lane = tid & 63, w = tid >> 6;
  int l15 = lane & 15, quad = lane >> 4;
  int wr = w >> 2, wc = w & 3;
  __syncthreads();
#pragma unroll
  for (int mh = 0; mh < 2; mh++)
#pragma unroll
    for (int mi = 0; mi < 4; mi++)
#pragma unroll
      for (int ni = 0; ni < 4; ni++) {
        int col = wc * 64 + ni * 16 + l15;
#pragma unroll
        for (int r = 0; r < 4; r++) {
          int row = wr * 128 + mh * 64 + mi * 16 + quad * 4 + r;
          int colsw = col ^ (((row >> 2) & 3) << 3);
          SM[row * 256 + colsw] = (_Float16)__expf(acc[mh * 4 + mi][ni][r]);
        }
      }
  __syncthreads();
  int c32 = lane & 31, hs = lane >> 5;
#pragma unroll
  for (int it = 0; it < 16; it++) {
    int row = w * 32 + it * 2 + hs;
    int cs = (c32 * 8) ^ (((row >> 2) & 3) << 3);
    half8 v = *(const half8*)&SM[row * 256 + cs];
    float s = 0.f;
#pragma unroll
    for (int j = 0; j < 8; j++) s += (float)v[j];
#pragma unroll
    for (int off = 1; off <= 16; off <<= 1) s += __shfl_xor(s, off, 64);
    *(half8*)&Eout[(size_t)h * 4194304 + (size_t)row * TALL + nt * 256 + c32 * 8] = v;
    if (c32 == 0) zframe[(size_t)(h * 256 + row) * 64 + nt] = s;
  }
}

// ---------------- PH gemm (257 blocks: 256 GEMM + 1 csoftmax) -------------
__launch_bounds__(512, 2)
__global__ void gemm256_ph_kernel(const _Float16* __restrict__ E, const _Float16* __restrict__ histT,
                                  const float* __restrict__ zframe, const float* __restrict__ dil_w,
                                  float* __restrict__ w4, char* __restrict__ ws) {
  __shared__ __align__(16) _Float16 SM[65536];
  int bid = blockIdx.x, tid = threadIdx.x;
  if (bid == 256) {                        // csoftmax: zframe -> w4
    float w0 = dil_w[0], w1 = dil_w[1], w2 = dil_w[2], w3 = dil_w[3];
    float wmx = fmaxf(fmaxf(w0, w1), fmaxf(w2, w3));
    float e0 = __expf(w0 - wmx), e1 = __expf(w1 - wmx), e2 = __expf(w2 - wmx), e3 = __expf(w3 - wmx);
    float wsum = e0 + e1 + e2 + e3;
#pragma unroll
    for (int i = 0; i < 2; i++) {
      int row = i * 512 + tid;
      const float* z = zframe + (size_t)row * 64;
      float z1 = 0.f, z4 = 0.f, z8 = 0.f, z16 = 0.f;
#pragma unroll
      for (int f = 0; f < 64; f++) {
        float v = z[f];
        z1 += v;
        if (!(f & 3))  z4 += v;
        if (!(f & 7))  z8 += v;
        if (!(f & 15)) z16 += v;
      }
      float b0 = (e0 / wsum) / z1 * 256.0f;
      float b1 = (e1 / wsum) / z4 * 256.0f;
      float b2 = (e2 / wsum) / z8 * 256.0f;
      float b3 = (e3 / wsum) / z16 * 256.0f;
      float* wr = w4 + (size_t)row * 4;
      wr[0] = b0;
      wr[1] = b0 + b1;
      wr[2] = b0 + b1 + b2;
      wr[3] = b0 + b1 + b2 + b3;
    }
    return;
  }
  _Float16* As = SM;
  _Float16* Bs = SM + 32768;
  int xcd = bid & 7, slot = bid >> 3;
  int g = xcd + 8 * (slot >> 4);
  int member = slot & 15;
  int h = member >> 2, nt = member & 3;
  const _Float16* A = E + (size_t)h * 4194304;
  const _Float16* B = histT + (size_t)(nt * 256) * TALL;
  floatx4 acc[8][4];
  floatx4 zero = {0.f, 0.f, 0.f, 0.f};
#pragma unroll
  for (int a = 0; a < 8; a++)
#pragma unroll
    for (int b = 0; b < 4; b++) acc[a][b] = zero;
  gemm256_run(A, TALL, B, TALL, ClsOff{g}, As, Bs, tid, acc);
  int lane = tid & 63, w = tid >> 6;
  int l15 = lane & 15, quad = lane >> 4;
  int wr = w >> 2, wc = w & 3;
  __syncthreads();
#pragma unroll
  for (int mh = 0; mh < 2; mh++)
#pragma unroll
    for (int mi = 0; mi < 4; mi++)
#pragma unroll
      for (int ni = 0; ni < 4; ni++) {
        int col = wc * 64 + ni * 16 + l15;
#pragma unroll
        for (int r = 0; r < 4; r++) {
          int row = wr * 128 + mh * 64 + mi * 16 + quad * 4 + r;
          int colsw = col ^ (((row >> 2) & 3) << 3);
          SM[row * 256 + colsw] = (_Float16)acc[mh * 4 + mi][ni][r];
        }
      }
  __syncthreads();
  _Float16* chunk = (_Float16*)(ws + chunk16_off(g));
  int c32 = lane & 31, hs = lane >> 5;
  int colbase = h * 1024 + nt * 256;
#pragma unroll
  for (int it = 0; it < 16; it++) {
    int row = w * 32 + it * 2 + hs;
    int cs = (c32 * 8) ^ (((row >> 2) & 3) << 3);
    half8 v = *(const half8*)&SM[row * 256 + cs];
    *(half8*)&chunk[(size_t)row * 4096 + colbase + c32 * 8] = v;
  }
}

// ---------------- reduce: 4 class sums x per-(h,q) weights -> PHred -------
__global__ void reduce_ph_kernel(const char* __restrict__ ws, const float* __restrict__ w4,
                                 _Float16* __restrict__ PHred) {
  size_t e8 = ((size_t)blockIdx.x * 256 + threadIdx.x) * 8;
  int q = (int)(e8 >> 12);
  int h = (int)((e8 >> 10) & 3);
  const float* wr = w4 + (size_t)(h * 256 + q) * 4;
  float sA[8] = {0,0,0,0,0,0,0,0}, sB[8] = {0,0,0,0,0,0,0,0};
  float sC[8] = {0,0,0,0,0,0,0,0}, sD[8] = {0,0,0,0,0,0,0,0};
#pragma unroll
  for (int g = 0; g < 12; g++) {
    const _Float16* p = (const _Float16*)(ws + chunk16_off(g));
    half8 v = *(const half8*)&p[e8];
#pragma unroll
    for (int j = 0; j < 8; j++) sA[j] += (float)v[j];
  }
#pragma unroll
  for (int g = 12; g < 14; g++) {
    const _Float16* p = (const _Float16*)(ws + chunk16_off(g));
    half8 v = *(const half8*)&p[e8];
#pragma unroll
    for (int j = 0; j < 8; j++) sB[j] += (float)v[j];
  }
  {
    const _Float16* p = (const _Float16*)(ws + chunk16_off(14));
    half8 v = *(const half8*)&p[e8];
#pragma unroll
    for (int j = 0; j < 8; j++) sC[j] += (float)v[j];
  }
  {
    const _Float16* p = (const _Float16*)(ws + chunk16_off(15));
    half8 v = *(const half8*)&p[e8];
#pragma unroll
    for (int j = 0; j < 8; j++) sD[j] += (float)v[j];
  }
  float wA = wr[0], wB = wr[1], wC = wr[2], wD = wr[3];
  half8 o;
#pragma unroll
  for (int j = 0; j < 8; j++)
    o[j] = (_Float16)(wA * sA[j] + wB * sB[j] + wC * sC[j] + wD * sD[j]);
  *(half8*)&PHred[e8] = o;
}

// ---------------- FO 16-way reduce + bo + bv@Wo + residual + layernorm ----
__global__ void ln_kernel(const float* __restrict__ x, const float* __restrict__ part2,
                          const float* __restrict__ bo, const float* __restrict__ bvwo,
                          const float* __restrict__ gamma, const float* __restrict__ beta,
                          float* __restrict__ out) {
  int b = blockIdx.x, t = threadIdx.x;
  __shared__ float red[8];
  float y[4];
  float sum = 0.f, sq = 0.f;
#pragma unroll
  for (int i = 0; i < 4; i++) {
    int j = t + i * 256;
    float v = x[(size_t)b * 1024 + j] + bo[j] + bvwo[j];
#pragma unroll
    for (int z = 0; z < 16; z++) v += part2[(size_t)z * 262144 + (size_t)b * 1024 + j];
    y[i] = v;
    sum += v;
    sq += v * v;
  }
#pragma unroll
  for (int off = 1; off < 64; off <<= 1) {
    sum += __shfl_xor(sum, off, 64);
    sq += __shfl_xor(sq, off, 64);
  }
  int w = t >> 6, lane = t & 63;
  if (lane == 0) { red[w] = sum; red[4 + w] = sq; }
  __syncthreads();
  sum = red[0] + red[1] + red[2] + red[3];
  sq = red[4] + red[5] + red[6] + red[7];
  float mu = sum * (1.f / 1024.f);
  float var = sq * (1.f / 1024.f) - mu * mu;
  float inv = rsqrtf(var + 1e-5f);
#pragma unroll
  for (int i = 0; i < 4; i++) {
    int j = t + i * 256;
    out[(size_t)b * 1024 + j] = (y[i] - mu) * inv * gamma[j] + beta[j];
  }
}

// ---------------- host launch ----------------
extern "C" void kernel_launch(void* const* d_in, const int* in_sizes, int n_in,
                              void* d_out, int out_size, void* d_ws, size_t ws_size,
                              hipStream_t stream) {
  const float* x     = (const float*)d_in[0];
  const float* hist  = (const float*)d_in[1];
  const float* Wq    = (const float*)d_in[2];
  const float* bq    = (const float*)d_in[3];
  const float* Wk    = (const float*)d_in[4];
  // bk (d_in[5]) dropped exactly: softmax shift invariance.
  const float* Wv    = (const float*)d_in[6];
  const float* bv    = (const float*)d_in[7];
  const float* Wo    = (const float*)d_in[8];
  const float* bo    = (const float*)d_in[9];
  const float* dil_w = (const float*)d_in[10];
  const float* gamma = (const float*)d_in[11];
  const float* beta  = (const float*)d_in[12];
  char* ws = (char*)d_ws;

  _Float16* WoT   = (_Float16*)(ws + OFF_WOT);
  _Float16* Wv16  = (_Float16*)(ws + OFF_WV16);
  _Float16* Wk16  = (_Float16*)(ws + OFF_WK16);
  _Float16* Wq16  = (_Float16*)(ws + OFF_WQ16);
  _Float16* xb    = (_Float16*)(ws + OFF_XB);
  _Float16* G     = (_Float16*)(ws + OFF_G);
  _Float16* WVOT  = (_Float16*)(ws + OFF_WVOT);
  _Float16* WQKT  = (_Float16*)(ws + OFF_WQKT);
  float* bvwo     = (float*)(ws + OFF_BVWO);
  float* bqk      = (float*)(ws + OFF_BQK);
  _Float16* PHred = (_Float16*)(ws + OFF_PHR);
  float* oppart   = (float*)(ws + OFF_OPP);    // 16 MB (OPP + dead histb head)
  _Float16* histb = (_Float16*)(ws + OFF_HB);
  _Float16* histT = (_Float16*)(ws + OFF_HT);
  _Float16* Eb    = (_Float16*)(ws + OFF_S);
  float* gpart    = (float*)(ws + OFF_S);      // 16 MB; dead before S writes Eb
  float* zframe   = (float*)(ws + OFF_PHR);    // 256 KB in PHR (no chunk overlap)
  float* w4       = (float*)(ws + OFF_G);      // 16 KB; G dead after S

  // 1) prep
  prep_kernel<<<dim3(8448), 256, 0, stream>>>(Wo, Wv, Wk, Wq, x, hist,
                                              WoT, Wv16, Wk16, Wq16, xb, histb, histT);
  // 2) wpack
  wpack_kernel<<<dim3(532), 256, 0, stream>>>(WoT, Wv16, Wk16, Wq16, bv, bq,
                                              WVOT, WQKT, bvwo, bqk);
  // 3) G split-K-4 partials (256 blocks) + reduce
  gemm_g_kernel<<<dim3(8, 2, 16), 256, 0, stream>>>(xb, WQKT, gpart);
  reduce_g_kernel<<<dim3(1024), 256, 0, stream>>>(gpart, bqk, G);
  // 4) E = exp(G @ hist^T) + Zframe
  gemm256_s_kernel<<<dim3(256), 512, 0, stream>>>(G, histb, Eb, zframe);
  // 5) PH class-partials (+ csoftmax block 256)
  gemm256_ph_kernel<<<dim3(257), 512, 0, stream>>>(Eb, histT, zframe, dil_w, w4, ws);
  // 6) reduce: class sums x w4 -> PHred
  reduce_ph_kernel<<<dim3(512), 256, 0, stream>>>(ws, w4, PHred);
  // 7) FO split-16 (256 blocks)
  gemm_f16_kernel<true><<<dim3(8, 2, 16), 256, 0, stream>>>(
      PHred, 4096, 256, WVOT, 4096, 256, 8, nullptr, 0, 1.0f / 256.0f,
      (void*)oppart, 1024, 262144);
  // 8) 16-way reduce + bo + bv@Wo + residual + layernorm
  ln_kernel<<<dim3(256), 256, 0, stream>>>(x, oppart, bo, bvwo, gamma, beta, (float*)d_out);
}

// Round 16
// 297.996 us; speedup vs baseline: 1.0672x; 1.0092x over previous
//
#include <hip/hip_runtime.h>

// TemporalDilatedAttention on gfx950 — round 22
// vs R21 (PASSED 300.7us, best): PH per-tile time 3576 cyc vs ~1400 cyc
// LDS+MFMA floor — the gap is lockstep rendezvous stall, unfillable at
// 1 block/CU (128KB LDS). R22: PH rebuilt as 256x128-tile / 4-wave (2x2,
// wave-tile 128x64 => SAME arithmetic intensity) / 2-buf 64KB LDS /
// launch_bounds(256,2) => 512 blocks at 2 blocks/CU — a second resident
// block fills the stalls. Ledger = proven R9 2-buf (stage t+2 into the
// just-read buf after lgkmcnt(0)+barrier; entry vmcnt(6), 6 gl_lds/stage
// at 256 threads). XCD pin g=(bid&7)+8*(slot>>5): 32 sharers co-XCD,
// 64 blocks = exactly 2/CU per XCD. Chunks/foff/reduce unchanged
// (colbase = h*1024 + nt*128); csoftmax now block 512 (grid 513x256).
// S untouched this round (one kernel at a time).

#define DD    1024
#define TALL  16384

typedef _Float16 half8  __attribute__((ext_vector_type(8)));
typedef _Float16 half4v __attribute__((ext_vector_type(4)));
typedef float    floatx4 __attribute__((ext_vector_type(4)));
typedef unsigned int u32;

// ---------------- workspace layout (bytes), ~132.5 MB ----------------
static const size_t OFF_WOT  = 0;          // 2 MB  Wo^T f16
static const size_t OFF_WV16 = 2097152;    // 2 MB  Wv f16
static const size_t OFF_WK16 = 4194304;    // 2 MB  Wk f16
static const size_t OFF_WQ16 = 6291456;    // 2 MB  Wq f16
static const size_t OFF_XB   = 8388608;    // 0.5 MB x f16
static const size_t OFF_G    = 8912896;    // 2 MB  G f16; w4 table after S
static const size_t OFF_WVOT = 11010048;   // 8 MB  WVOT f16 (LIVE through FO)
static const size_t OFF_WQKT = 19398656;   // 8 MB  WQKT f16 (dead after G; chunks 4-7 here)
static const size_t OFF_BVWO = 27787264;   // 4 KB  bv@Wo f32
static const size_t OFF_BQK  = 27791360;   // 16 KB bqk f32
static const size_t OFF_PHR  = 27807744;   // 2 MB  zframe (S->PH), then PHred f16
static const size_t OFF_OPP  = 29904896;   // 16 MB FO partials f32 (spills into dead histb head)
static const size_t OFF_HB   = 38293504;   // 32 MB histb (dead after S)
static const size_t OFF_HT   = 71848960;   // 32 MB hist^T f16 [feat][t]
static const size_t OFF_S    = 105403392;  // 32 MB: G split-K partials (16MB) then E f16

// PH f16 partial chunks: 16 x 2 MB over regions dead during launches 5-6.
__device__ __forceinline__ size_t chunk16_off(int g) {
  if (g < 4)  return (size_t)g * 2097152;
  if (g < 8)  return 19398656 + (size_t)(g - 4) * 2097152;
  if (g < 12) return 29904896 + (size_t)(g - 8) * 2097152;
  return 38293504 + (size_t)(g - 12) * 2097152;
}

// Frame-class chunk map: chunk g, sub-frame j (0..3) -> frame index.
__device__ __forceinline__ int frame_of(int g, int j) {
  if (g < 12) { int m = g * 4 + j; return m + m / 3 + 1; }
  if (g < 14) return 4 + 8 * ((g - 12) * 4 + j);
  if (g == 14) return 8 + 16 * j;
  return 16 * j;
}
__device__ __forceinline__ size_t foff(int g, int t) {
  return (size_t)frame_of(g, t >> 3) * 512 + (size_t)(t & 7) * 64;
}

// ---------------- async global->LDS, 16B per lane ----------------
__device__ __forceinline__ void gl_lds16(const void* g, void* l) {
  __builtin_amdgcn_global_load_lds((const __attribute__((address_space(1))) u32*)g,
                                   (__attribute__((address_space(3))) u32*)l, 16, 0, 0);
}

// ---------------- prep (unchanged) ----------------
__global__ void prep_kernel(const float* __restrict__ Wo, const float* __restrict__ Wv,
                            const float* __restrict__ Wk, const float* __restrict__ Wq,
                            const float* __restrict__ x, const float* __restrict__ hist,
                            _Float16* __restrict__ WoT, _Float16* __restrict__ Wv16,
                            _Float16* __restrict__ Wk16, _Float16* __restrict__ Wq16,
                            _Float16* __restrict__ xb, _Float16* __restrict__ histb,
                            _Float16* __restrict__ histT) {
  int bid = blockIdx.x, tid = threadIdx.x;
  if (bid < 1024) {                        // Wo transpose+cvt
    int k0 = (bid & 31) * 32, n0 = (bid >> 5) * 32;
    __shared__ float t32[32][33];
    int tx = tid & 31, ty = tid >> 5;
#pragma unroll
    for (int i = 0; i < 4; i++) {
      int r = ty + i * 8;
      t32[r][tx] = Wo[(size_t)(k0 + r) * DD + n0 + tx];
    }
    __syncthreads();
#pragma unroll
    for (int i = 0; i < 4; i++) {
      int r = ty + i * 8;
      WoT[(size_t)(n0 + r) * DD + k0 + tx] = (_Float16)t32[tx][r];
    }
  } else if (bid < 4352) {                 // plain cvt
    const float* src; _Float16* dst; size_t i;
    if (bid < 2048)      { src = Wv; dst = Wv16; i = (size_t)(bid - 1024) * 256 + tid; }
    else if (bid < 3072) { src = Wk; dst = Wk16; i = (size_t)(bid - 2048) * 256 + tid; }
    else if (bid < 4096) { src = Wq; dst = Wq16; i = (size_t)(bid - 3072) * 256 + tid; }
    else                 { src = x;  dst = xb;   i = (size_t)(bid - 4096) * 256 + tid; }
    float4 v = ((const float4*)src)[i];
    half4v h = {(_Float16)v.x, (_Float16)v.y, (_Float16)v.z, (_Float16)v.w};
    *(half4v*)(dst + 4 * i) = h;
  } else {                                 // hist dual write
    int tb = bid - 4352;
    int t0 = (tb & 255) * 64, f0 = (tb >> 8) * 64;
    __shared__ _Float16 lt[64][72];
    int r = tid >> 2, c0 = (tid & 3) * 16;
    half8 s0, s1;
#pragma unroll
    for (int i = 0; i < 4; i++) {
      float4 v = *(const float4*)&hist[(size_t)(t0 + r) * 1024 + f0 + c0 + i * 4];
      half4v h = {(_Float16)v.x, (_Float16)v.y, (_Float16)v.z, (_Float16)v.w};
      *(half4v*)&lt[r][c0 + i * 4] = h;
      if (i < 2) { s0[i*4]=h[0]; s0[i*4+1]=h[1]; s0[i*4+2]=h[2]; s0[i*4+3]=h[3]; }
      else { s1[(i-2)*4]=h[0]; s1[(i-2)*4+1]=h[1]; s1[(i-2)*4+2]=h[2]; s1[(i-2)*4+3]=h[3]; }
    }
    *(half8*)&histb[(size_t)(t0 + r) * 1024 + f0 + c0] = s0;
    *(half8*)&histb[(size_t)(t0 + r) * 1024 + f0 + c0 + 8] = s1;
    __syncthreads();
    int fr = tid >> 2, tc0 = (tid & 3) * 16;
    half8 o0, o1;
#pragma unroll
    for (int j = 0; j < 8; j++) { o0[j] = lt[tc0 + j][fr]; o1[j] = lt[tc0 + 8 + j][fr]; }
    *(half8*)&histT[(size_t)(f0 + fr) * TALL + t0 + tc0] = o0;
    *(half8*)&histT[(size_t)(f0 + fr) * TALL + t0 + tc0 + 8] = o1;
  }
}

// ---------------- R9 128x128 core (wpack/G/FO) ----------------------------
__device__ __forceinline__ void gemm_core(const _Float16* __restrict__ A, size_t lda,
                                          const _Float16* __restrict__ B, size_t ldb,
                                          int kIters, _Float16* As, _Float16* Bs,
                                          int tid, floatx4 acc[4][4]) {
  int lane = tid & 63, w = tid >> 6;
  int l15 = lane & 15, quad = lane >> 4;
  int wm = (w >> 1) * 64, wn = (w & 1) * 64;
  int swz = ((tid & 3) ^ ((tid >> 3) & 3)) * 8;
  int pch = (quad ^ ((l15 >> 1) & 3)) * 8;
  const char* gA0 = (const char*)(A + (size_t)(tid >> 2) * lda + swz);
  const char* gA1 = (const char*)(A + ((size_t)(tid >> 2) + 64) * lda + swz);
  const char* gB0 = (const char*)(B + (size_t)(tid >> 2) * ldb + swz);
  const char* gB1 = (const char*)(B + ((size_t)(tid >> 2) + 64) * ldb + swz);
  _Float16* lA = As + w * 512;
  _Float16* lB = Bs + w * 512;
#define GC_STAGE(buf, k)                                    \
  do {                                                      \
    size_t off_ = (size_t)(k) * 64;                         \
    gl_lds16(gA0 + off_, lA + (buf) * 4096);                \
    gl_lds16(gA1 + off_, lA + (buf) * 4096 + 2048);         \
    gl_lds16(gB0 + off_, lB + (buf) * 4096);                \
    gl_lds16(gB1 + off_, lB + (buf) * 4096 + 2048);         \
  } while (0)
#define GC_STEP(buf, k)                                                       \
  do {                                                                        \
    if ((k) + 1 < kIters) asm volatile("s_waitcnt vmcnt(4)" ::: "memory");    \
    else                  asm volatile("s_waitcnt vmcnt(0)" ::: "memory");    \
    asm volatile("s_barrier" ::: "memory");                                   \
    const _Float16* Ac_ = As + (buf) * 4096;                                  \
    const _Float16* Bc_ = Bs + (buf) * 4096;                                  \
    half8 a_[4];                                                              \
    _Pragma("unroll")                                                         \
    for (int mi = 0; mi < 4; mi++)                                            \
      a_[mi] = *(const half8*)&Ac_[(wm + mi * 16 + l15) * 32 + pch];          \
    _Pragma("unroll")                                                         \
    for (int ni = 0; ni < 4; ni++) {                                          \
      half8 b8_ = *(const half8*)&Bc_[(wn + ni * 16 + l15) * 32 + pch];       \
      _Pragma("unroll")                                                       \
      for (int mi = 0; mi < 4; mi++)                                          \
        acc[mi][ni] = __builtin_amdgcn_mfma_f32_16x16x32_f16(a_[mi], b8_,     \
                                                             acc[mi][ni], 0, 0, 0); \
    }                                                                         \
    asm volatile("s_waitcnt lgkmcnt(0)" ::: "memory");                        \
    asm volatile("s_barrier" ::: "memory");                                   \
    if ((k) + 2 < kIters) GC_STAGE(buf, (k) + 2);                             \
  } while (0)
  GC_STAGE(0, 0);
  GC_STAGE(1, 1);
  for (int kk = 0; kk < kIters; kk += 2) {
    GC_STEP(0, kk);
    GC_STEP(1, kk + 1);
  }
#undef GC_STEP
#undef GC_STAGE
}

// ---------------- 256x256 8-wave minimal-barrier core (S) -----------------
template <typename OFF>
__device__ __forceinline__ void gemm256_run(const _Float16* __restrict__ A, size_t lda,
                                            const _Float16* __restrict__ B, size_t ldb,
                                            OFF off, _Float16* As, _Float16* Bs,
                                            int tid, floatx4 acc[8][4]) {
  int lane = tid & 63, w = tid >> 6;
  int l15 = lane & 15, quad = lane >> 4;
  int wr = w >> 2, wc = w & 3;
  int pch = (quad ^ ((l15 >> 1) & 3)) * 8;
  int srow = tid >> 2;
  int schunk = (tid & 3) ^ ((tid >> 3) & 3);
  const char* gA0 = (const char*)(A + (size_t)srow * lda + schunk * 8);
  const char* gA1 = (const char*)(A + (size_t)(srow + 128) * lda + schunk * 8);
  const char* gB0 = (const char*)(B + (size_t)srow * ldb + schunk * 8);
  const char* gB1 = (const char*)(B + (size_t)(srow + 128) * ldb + schunk * 8);
  _Float16* lA = As + w * 512;
  _Float16* lB = Bs + w * 512;
#define PSTA(buf, t)                                          \
  do { size_t o_ = off(t);                                    \
    gl_lds16(gA0 + o_, lA + (buf) * 8192);                    \
    gl_lds16(gA1 + o_, lA + (buf) * 8192 + 4096);             \
  } while (0)
#define PSTB(buf, t)                                          \
  do { size_t o_ = off(t);                                    \
    gl_lds16(gB0 + o_, lB + (buf) * 8192);                    \
    gl_lds16(gB1 + o_, lB + (buf) * 8192 + 4096);             \
  } while (0)
  PSTA(0, 0); PSTB(0, 0);
  PSTA(1, 1); PSTB(1, 1);
  PSTA(2, 2); PSTB(2, 2);
  for (int t = 0; t < 32; ++t) {
    int buf = t & 3;
    if (t + 2 < 32)      asm volatile("s_waitcnt vmcnt(8)" ::: "memory");
    else if (t + 1 < 32) asm volatile("s_waitcnt vmcnt(4)" ::: "memory");
    else                 asm volatile("s_waitcnt vmcnt(0)" ::: "memory");
    asm volatile("s_barrier" ::: "memory");
    const _Float16* Ac = As + buf * 8192;
    const _Float16* Bc = Bs + buf * 8192;
    half8 b8[4], a8[4];
#pragma unroll
    for (int ni = 0; ni < 4; ni++)
      b8[ni] = *(const half8*)&Bc[(wc * 64 + ni * 16 + l15) * 32 + pch];
#pragma unroll
    for (int mi = 0; mi < 4; mi++)
      a8[mi] = *(const half8*)&Ac[(wr * 128 + mi * 16 + l15) * 32 + pch];
    if (t + 3 < 32) PSTA((t + 3) & 3, t + 3);
    asm volatile("s_waitcnt lgkmcnt(0)" ::: "memory");
    __builtin_amdgcn_s_setprio(1);
#pragma unroll
    for (int mi = 0; mi < 4; mi++)
#pragma unroll
      for (int ni = 0; ni < 4; ni++)
        acc[mi][ni] = __builtin_amdgcn_mfma_f32_16x16x32_f16(a8[mi], b8[ni], acc[mi][ni], 0, 0, 0);
    __builtin_amdgcn_s_setprio(0);
#pragma unroll
    for (int mi = 0; mi < 4; mi++)
      a8[mi] = *(const half8*)&Ac[(wr * 128 + 64 + mi * 16 + l15) * 32 + pch];
    if (t + 3 < 32) PSTB((t + 3) & 3, t + 3);
    asm volatile("s_waitcnt lgkmcnt(0)" ::: "memory");
    __builtin_amdgcn_s_setprio(1);
#pragma unroll
    for (int mi = 0; mi < 4; mi++)
#pragma unroll
      for (int ni = 0; ni < 4; ni++)
        acc[4 + mi][ni] = __builtin_amdgcn_mfma_f32_16x16x32_f16(a8[mi], b8[ni], acc[4 + mi][ni], 0, 0, 0);
    __builtin_amdgcn_s_setprio(0);
  }
#undef PSTA
#undef PSTB
}

struct LinOff { __device__ __forceinline__ size_t operator()(int t) const { return (size_t)t * 64; } };
struct ClsOff { int g; __device__ __forceinline__ size_t operator()(int t) const { return foff(g, t); } };

// ---------------- generic single-B GEMM (R9 core) ----------------
template <bool OUTF32>
__launch_bounds__(256, 3)
__global__ void gemm_f16_kernel(const _Float16* __restrict__ A, size_t lda, size_t aoffz,
                                const _Float16* __restrict__ B, size_t ldb, size_t boffz,
                                int kIters, const float* __restrict__ bias, size_t biasoffz,
                                float scale, void* __restrict__ C, size_t ldc, size_t coffz) {
  __shared__ __align__(16) _Float16 As[8192];
  __shared__ __align__(16) _Float16 Bs[8192];
  int tid = threadIdx.x;
  const _Float16* Ab = A + aoffz * blockIdx.z + (size_t)(blockIdx.y * 128) * lda;
  const _Float16* Bb = B + boffz * blockIdx.z + (size_t)(blockIdx.x * 128) * ldb;
  floatx4 acc[4][4];
  floatx4 zero = {0.f, 0.f, 0.f, 0.f};
#pragma unroll
  for (int a = 0; a < 4; a++)
#pragma unroll
    for (int b = 0; b < 4; b++) acc[a][b] = zero;
  gemm_core(Ab, lda, Bb, ldb, kIters, As, Bs, tid, acc);
  int lane = tid & 63, w = tid >> 6;
  int l15 = lane & 15, quad = lane >> 4;
  int wm = (w >> 1) * 64, wn = (w & 1) * 64;
#pragma unroll
  for (int mi = 0; mi < 4; mi++)
#pragma unroll
    for (int ni = 0; ni < 4; ni++) {
      int colg = blockIdx.x * 128 + wn + ni * 16 + l15;
      float bv = bias ? bias[biasoffz * blockIdx.z + colg] : 0.f;
#pragma unroll
      for (int r = 0; r < 4; r++) {
        int rowg = blockIdx.y * 128 + wm + mi * 16 + quad * 4 + r;
        float v = (acc[mi][ni][r] + bv) * scale;
        size_t idx = coffz * blockIdx.z + (size_t)rowg * ldc + colg;
        if (OUTF32) ((float*)C)[idx] = v;
        else ((_Float16*)C)[idx] = (_Float16)v;
      }
    }
}

// ---------------- G gemm, split-K-4: z = sp*4 + h, 256 blocks -------------
__launch_bounds__(256, 3)
__global__ void gemm_g_kernel(const _Float16* __restrict__ xb, const _Float16* __restrict__ WQKT,
                              float* __restrict__ gpart) {
  __shared__ __align__(16) _Float16 As[8192];
  __shared__ __align__(16) _Float16 Bs[8192];
  int tid = threadIdx.x;
  int z = blockIdx.z, sp = z >> 2, h = z & 3;
  const _Float16* Ab = xb + sp * 256 + (size_t)(blockIdx.y * 128) * 1024;
  const _Float16* Bb = WQKT + (size_t)h * 1048576 + sp * 256 + (size_t)(blockIdx.x * 128) * 1024;
  floatx4 acc[4][4];
  floatx4 zero = {0.f, 0.f, 0.f, 0.f};
#pragma unroll
  for (int a = 0; a < 4; a++)
#pragma unroll
    for (int b = 0; b < 4; b++) acc[a][b] = zero;
  gemm_core(Ab, 1024, Bb, 1024, 8, As, Bs, tid, acc);
  int lane = tid & 63, w = tid >> 6;
  int l15 = lane & 15, quad = lane >> 4;
  int wm = (w >> 1) * 64, wn = (w & 1) * 64;
#pragma unroll
  for (int mi = 0; mi < 4; mi++)
#pragma unroll
    for (int ni = 0; ni < 4; ni++) {
      int col = blockIdx.x * 128 + wn + ni * 16 + l15;
#pragma unroll
      for (int r = 0; r < 4; r++) {
        int row = blockIdx.y * 128 + wm + mi * 16 + quad * 4 + r;
        gpart[(size_t)z * 262144 + (size_t)row * 1024 + col] = acc[mi][ni][r];
      }
    }
}

// ---------------- reduce_g: 4 sp-partials + bqk -> G f16 ------------------
__global__ void reduce_g_kernel(const float* __restrict__ gpart, const float* __restrict__ bqk,
                                _Float16* __restrict__ G) {
  size_t e4 = ((size_t)blockIdx.x * 256 + threadIdx.x) * 4;   // 1024 blocks
  int h = (int)(e4 >> 18);
  size_t rem = e4 & 262143;
  int d = (int)(e4 & 1023);
  float4 s = *(const float4*)&bqk[h * 1024 + d];
#pragma unroll
  for (int sp = 0; sp < 4; sp++) {
    float4 p = *(const float4*)&gpart[(size_t)(sp * 4 + h) * 262144 + rem];
    s.x += p.x; s.y += p.y; s.z += p.z; s.w += p.w;
  }
  half4v o = {(_Float16)s.x, (_Float16)s.y, (_Float16)s.z, (_Float16)s.w};
  *(half4v*)&G[e4] = o;
}

// ---------------- wpack (unchanged, R9 core) ----------------
__launch_bounds__(256, 3)
__global__ void wpack_kernel(const _Float16* __restrict__ WoT, const _Float16* __restrict__ Wv16,
                             const _Float16* __restrict__ Wk16, const _Float16* __restrict__ Wq16,
                             const float* __restrict__ bv, const float* __restrict__ bq,
                             _Float16* __restrict__ WVOT, _Float16* __restrict__ WQKT,
                             float* __restrict__ bvwo, float* __restrict__ bqk) {
  __shared__ __align__(16) _Float16 As[8192];
  __shared__ __align__(16) _Float16 Bs[8192];
  int bid = blockIdx.x, tid = threadIdx.x;
  if (bid < 512) {
    bool isQK = bid >= 256;
    int g = bid & 255;
    int x = g & 7, y = (g >> 3) & 7, z = g >> 6;
    const _Float16* A = isQK ? Wk16 : WoT;
    const _Float16* B = isQK ? Wq16 : Wv16;
    const _Float16* Ab = A + 256 * z + (size_t)(y * 128) * 1024;
    const _Float16* Bb = B + 256 * z + (size_t)(x * 128) * 1024;
    floatx4 acc[4][4];
    floatx4 zero = {0.f, 0.f, 0.f, 0.f};
#pragma unroll
    for (int a = 0; a < 4; a++)
#pragma unroll
      for (int b = 0; b < 4; b++) acc[a][b] = zero;
    gemm_core(Ab, 1024, Bb, 1024, 8, As, Bs, tid, acc);
    float scale = isQK ? 0.0625f : 1.0f;
    _Float16* C = isQK ? WQKT : WVOT;
    size_t ldc = isQK ? 1024 : 4096;
    size_t zoff = isQK ? (size_t)1048576 * z : (size_t)1024 * z;
    int lane = tid & 63, w = tid >> 6;
    int l15 = lane & 15, quad = lane >> 4;
    int wm = (w >> 1) * 64, wn = (w & 1) * 64;
#pragma unroll
    for (int mi = 0; mi < 4; mi++)
#pragma unroll
      for (int ni = 0; ni < 4; ni++) {
        int col = x * 128 + wn + ni * 16 + l15;
#pragma unroll
        for (int r = 0; r < 4; r++) {
          int row = y * 128 + wm + mi * 16 + quad * 4 + r;
          C[zoff + (size_t)row * ldc + col] = (_Float16)(acc[mi][ni][r] * scale);
        }
      }
  } else if (bid < 516) {
    int j = (bid - 512) * 256 + tid;
    const half8* row = (const half8*)(WoT + (size_t)j * 1024);
    float a = 0.f;
    for (int c = 0; c < 128; c++) {
      half8 w8 = row[c];
#pragma unroll
      for (int e = 0; e < 8; e++) a += bv[c * 8 + e] * (float)w8[e];
    }
    bvwo[j] = a;
  } else {
    int idx = (bid - 516) * 256 + tid;
    int h = idx >> 10, f = idx & 1023;
    const _Float16* row = Wk16 + (size_t)f * 1024 + h * 256;
    float a = 0.f;
    for (int n = 0; n < 256; n++) a += bq[h * 256 + n] * (float)row[n];
    bqk[idx] = a * 0.0625f;
  }
}

// ---------------- S gemm: minimal-barrier core + exp epilogue + Zframe ----
__launch_bounds__(512, 2)
__global__ void gemm256_s_kernel(const _Float16* __restrict__ G, const _Float16* __restrict__ histb,
                                 _Float16* __restrict__ Eout, float* __restrict__ zframe) {
  __shared__ __align__(16) _Float16 SM[65536];
  _Float16* As = SM;
  _Float16* Bs = SM + 32768;
  int bid = blockIdx.x, tid = threadIdx.x;
  int h = bid >> 6, nt = bid & 63;
  const _Float16* Ab = G + (size_t)h * 262144;
  const _Float16* Bb = histb + (size_t)(nt * 256) * 1024;
  floatx4 acc[8][4];
  floatx4 zero = {0.f, 0.f, 0.f, 0.f};
#pragma unroll
  for (int a = 0; a < 8; a++)
#pragma unroll
    for (int b = 0; b < 4; b++) acc[a][b] = zero;
  gemm256_run(Ab, 1024, Bb, 1024, LinOff{}, As, Bs, tid, acc);
  int lane = tid & 63, w = tid >> 6;
  int l15 = lane & 15, quad = lane >> 4;
  int wr = w >> 2, wc = w & 3;
  __syncthreads();
#pragma unroll
  for (int mh = 0; mh < 2; mh++)
#pragma unroll
    for (int mi = 0; mi < 4; mi++)
#pragma unroll
      for (int ni = 0; ni < 4; ni++) {
        int col = wc * 64 + ni * 16 + l15;
#pragma unroll
        for (int r = 0; r < 4; r++) {
          int row = wr * 128 + mh * 64 + mi * 16 + quad * 4 + r;
          int colsw = col ^ (((row >> 2) & 3) << 3);
          SM[row * 256 + colsw] = (_Float16)__expf(acc[mh * 4 + mi][ni][r]);
        }
      }
  __syncthreads();
  int c32 = lane & 31, hs = lane >> 5;
#pragma unroll
  for (int it = 0; it < 16; it++) {
    int row = w * 32 + it * 2 + hs;
    int cs = (c32 * 8) ^ (((row >> 2) & 3) << 3);
    half8 v = *(const half8*)&SM[row * 256 + cs];
    float s = 0.f;
#pragma unroll
    for (int j = 0; j < 8; j++) s += (float)v[j];
#pragma unroll
    for (int off = 1; off <= 16; off <<= 1) s += __shfl_xor(s, off, 64);
    *(half8*)&Eout[(size_t)h * 4194304 + (size_t)row * TALL + nt * 256 + c32 * 8] = v;
    if (c32 == 0) zframe[(size_t)(h * 256 + row) * 64 + nt] = s;
  }
}

// ---------------- PH gemm: 256x128 tile / 4-wave / 2-buf / 2 blocks/CU ----
// Grid 513 x 256 threads: bid<512 GEMM, bid==512 csoftmax.
// bid = slot*8 + xcd; g = xcd + 8*(slot>>5); member = slot&31;
// h = member>>3, nt = member&7 (128-col B slice). Ledger (R9 2-buf):
// entry vmcnt(6|0) [stage t landed, t+1's 6 in flight]; barrier; reads+MFMA;
// lgkmcnt(0); barrier; stage(t+2) into buf t&1 (just drained). LDS: A 2x8192
// + B 2x4096 = 48KB in a 64KB block (epilogue reuses full 64KB) -> 2/CU.
__launch_bounds__(256, 2)
__global__ void gemm256_ph_kernel(const _Float16* __restrict__ E, const _Float16* __restrict__ histT,
                                  const float* __restrict__ zframe, const float* __restrict__ dil_w,
                                  float* __restrict__ w4, char* __restrict__ ws) {
  __shared__ __align__(16) _Float16 SM[32768];   // 64 KB
  int bid = blockIdx.x, tid = threadIdx.x;
  if (bid == 512) {                        // csoftmax: zframe -> w4
    float w0 = dil_w[0], w1 = dil_w[1], w2 = dil_w[2], w3 = dil_w[3];
    float wmx = fmaxf(fmaxf(w0, w1), fmaxf(w2, w3));
    float e0 = __expf(w0 - wmx), e1 = __expf(w1 - wmx), e2 = __expf(w2 - wmx), e3 = __expf(w3 - wmx);
    float wsum = e0 + e1 + e2 + e3;
#pragma unroll
    for (int i = 0; i < 4; i++) {
      int row = i * 256 + tid;
      const float* z = zframe + (size_t)row * 64;
      float z1 = 0.f, z4 = 0.f, z8 = 0.f, z16 = 0.f;
#pragma unroll
      for (int f = 0; f < 64; f++) {
        float v = z[f];
        z1 += v;
        if (!(f & 3))  z4 += v;
        if (!(f & 7))  z8 += v;
        if (!(f & 15)) z16 += v;
      }
      float b0 = (e0 / wsum) / z1 * 256.0f;
      float b1 = (e1 / wsum) / z4 * 256.0f;
      float b2 = (e2 / wsum) / z8 * 256.0f;
      float b3 = (e3 / wsum) / z16 * 256.0f;
      float* wr = w4 + (size_t)row * 4;
      wr[0] = b0;
      wr[1] = b0 + b1;
      wr[2] = b0 + b1 + b2;
      wr[3] = b0 + b1 + b2 + b3;
    }
    return;
  }
  _Float16* As = SM;            // 2 bufs x 8192 f16 (256x32)
  _Float16* Bs = SM + 16384;    // 2 bufs x 4096 f16 (128x32)
  int xcd = bid & 7, slot = bid >> 3;
  int g = xcd + 8 * (slot >> 5);
  int member = slot & 31;
  int h = member >> 3, nt = member & 7;
  int lane = tid & 63, w = tid >> 6;
  int l15 = lane & 15, quad = lane >> 4;
  int wr = w >> 1, wc = w & 1;             // wave grid 2 (M) x 2 (N)
  int pch = (quad ^ ((l15 >> 1) & 3)) * 8;
  int srow = tid >> 2;                      // 0..63
  int schunk = (tid & 3) ^ ((tid >> 3) & 3);
  const _Float16* A = E + (size_t)h * 4194304;
  const _Float16* B = histT + (size_t)(nt * 128) * TALL;
  const char* gA0 = (const char*)(A + (size_t)srow * TALL + schunk * 8);
  const char* gA1 = (const char*)(A + (size_t)(srow + 64) * TALL + schunk * 8);
  const char* gA2 = (const char*)(A + (size_t)(srow + 128) * TALL + schunk * 8);
  const char* gA3 = (const char*)(A + (size_t)(srow + 192) * TALL + schunk * 8);
  const char* gB0 = (const char*)(B + (size_t)srow * TALL + schunk * 8);
  const char* gB1 = (const char*)(B + (size_t)(srow + 64) * TALL + schunk * 8);
  _Float16* lA = As + w * 512;              // 256 thr: wave covers 1KB per instr
  _Float16* lB = Bs + w * 512;
  floatx4 acc[8][4];
  floatx4 zero = {0.f, 0.f, 0.f, 0.f};
#pragma unroll
  for (int a = 0; a < 8; a++)
#pragma unroll
    for (int b = 0; b < 4; b++) acc[a][b] = zero;
#define HST(buf, t)                                           \
  do { size_t o_ = foff(g, t);                                \
    gl_lds16(gA0 + o_, lA + (buf) * 8192);                    \
    gl_lds16(gA1 + o_, lA + (buf) * 8192 + 2048);             \
    gl_lds16(gA2 + o_, lA + (buf) * 8192 + 4096);             \
    gl_lds16(gA3 + o_, lA + (buf) * 8192 + 6144);             \
    gl_lds16(gB0 + o_, lB + (buf) * 4096);                    \
    gl_lds16(gB1 + o_, lB + (buf) * 4096 + 2048);             \
  } while (0)
  HST(0, 0);
  HST(1, 1);
  for (int t = 0; t < 32; ++t) {
    int buf = t & 1;
    if (t + 1 < 32) asm volatile("s_waitcnt vmcnt(6)" ::: "memory");
    else            asm volatile("s_waitcnt vmcnt(0)" ::: "memory");
    asm volatile("s_barrier" ::: "memory");
    const _Float16* Ac = As + buf * 8192;
    const _Float16* Bc = Bs + buf * 4096;
    half8 b8[4], a8[8];
#pragma unroll
    for (int ni = 0; ni < 4; ni++)
      b8[ni] = *(const half8*)&Bc[(wc * 64 + ni * 16 + l15) * 32 + pch];
#pragma unroll
    for (int mi = 0; mi < 8; mi++)
      a8[mi] = *(const half8*)&Ac[(wr * 128 + mi * 16 + l15) * 32 + pch];
    asm volatile("s_waitcnt lgkmcnt(0)" ::: "memory");
    __builtin_amdgcn_s_setprio(1);
#pragma unroll
    for (int mi = 0; mi < 8; mi++)
#pragma unroll
      for (int ni = 0; ni < 4; ni++)
        acc[mi][ni] = __builtin_amdgcn_mfma_f32_16x16x32_f16(a8[mi], b8[ni], acc[mi][ni], 0, 0, 0);
    __builtin_amdgcn_s_setprio(0);
    asm volatile("s_barrier" ::: "memory");
    if (t + 2 < 32) HST(buf, t + 2);
  }
#undef HST
  // ---- epilogue: swizzled LDS transpose (256x128), logical-col stores ----
  __syncthreads();
#pragma unroll
  for (int mi = 0; mi < 8; mi++)
#pragma unroll
    for (int ni = 0; ni < 4; ni++) {
      int col = wc * 64 + ni * 16 + l15;
#pragma unroll
      for (int r = 0; r < 4; r++) {
        int row = wr * 128 + mi * 16 + quad * 4 + r;
        int colsw = col ^ (((row >> 2) & 3) << 3);
        SM[row * 128 + colsw] = (_Float16)acc[mi][ni][r];
      }
    }
  __syncthreads();
  _Float16* chunk = (_Float16*)(ws + chunk16_off(g));
  int c16 = lane & 15, rq = lane >> 4;
  int colbase = h * 1024 + nt * 128;
#pragma unroll
  for (int it = 0; it < 16; it++) {
    int row = w * 64 + it * 4 + rq;
    int cs = (c16 * 8) ^ (((row >> 2) & 3) << 3);   // physical LDS position
    half8 v = *(const half8*)&SM[row * 128 + cs];   // logical cols [c16*8, +8)
    *(half8*)&chunk[(size_t)row * 4096 + colbase + c16 * 8] = v;
  }
}

// ---------------- reduce: 4 class sums x per-(h,q) weights -> PHred -------
__global__ void reduce_ph_kernel(const char* __restrict__ ws, const float* __restrict__ w4,
                                 _Float16* __restrict__ PHred) {
  size_t e8 = ((size_t)blockIdx.x * 256 + threadIdx.x) * 8;
  int q = (int)(e8 >> 12);
  int h = (int)((e8 >> 10) & 3);
  const float* wr = w4 + (size_t)(h * 256 + q) * 4;
  float sA[8] = {0,0,0,0,0,0,0,0}, sB[8] = {0,0,0,0,0,0,0,0};
  float sC[8] = {0,0,0,0,0,0,0,0}, sD[8] = {0,0,0,0,0,0,0,0};
#pragma unroll
  for (int g = 0; g < 12; g++) {
    const _Float16* p = (const _Float16*)(ws + chunk16_off(g));
    half8 v = *(const half8*)&p[e8];
#pragma unroll
    for (int j = 0; j < 8; j++) sA[j] += (float)v[j];
  }
#pragma unroll
  for (int g = 12; g < 14; g++) {
    const _Float16* p = (const _Float16*)(ws + chunk16_off(g));
    half8 v = *(const half8*)&p[e8];
#pragma unroll
    for (int j = 0; j < 8; j++) sB[j] += (float)v[j];
  }
  {
    const _Float16* p = (const _Float16*)(ws + chunk16_off(14));
    half8 v = *(const half8*)&p[e8];
#pragma unroll
    for (int j = 0; j < 8; j++) sC[j] += (float)v[j];
  }
  {
    const _Float16* p = (const _Float16*)(ws + chunk16_off(15));
    half8 v = *(const half8*)&p[e8];
#pragma unroll
    for (int j = 0; j < 8; j++) sD[j] += (float)v[j];
  }
  float wA = wr[0], wB = wr[1], wC = wr[2], wD = wr[3];
  half8 o;
#pragma unroll
  for (int j = 0; j < 8; j++)
    o[j] = (_Float16)(wA * sA[j] + wB * sB[j] + wC * sC[j] + wD * sD[j]);
  *(half8*)&PHred[e8] = o;
}

// ---------------- FO 16-way reduce + bo + bv@Wo + residual + layernorm ----
__global__ void ln_kernel(const float* __restrict__ x, const float* __restrict__ part2,
                          const float* __restrict__ bo, const float* __restrict__ bvwo,
                          const float* __restrict__ gamma, const float* __restrict__ beta,
                          float* __restrict__ out) {
  int b = blockIdx.x, t = threadIdx.x;
  __shared__ float red[8];
  float y[4];
  float sum = 0.f, sq = 0.f;
#pragma unroll
  for (int i = 0; i < 4; i++) {
    int j = t + i * 256;
    float v = x[(size_t)b * 1024 + j] + bo[j] + bvwo[j];
#pragma unroll
    for (int z = 0; z < 16; z++) v += part2[(size_t)z * 262144 + (size_t)b * 1024 + j];
    y[i] = v;
    sum += v;
    sq += v * v;
  }
#pragma unroll
  for (int off = 1; off < 64; off <<= 1) {
    sum += __shfl_xor(sum, off, 64);
    sq += __shfl_xor(sq, off, 64);
  }
  int w = t >> 6, lane = t & 63;
  if (lane == 0) { red[w] = sum; red[4 + w] = sq; }
  __syncthreads();
  sum = red[0] + red[1] + red[2] + red[3];
  sq = red[4] + red[5] + red[6] + red[7];
  float mu = sum * (1.f / 1024.f);
  float var = sq * (1.f / 1024.f) - mu * mu;
  float inv = rsqrtf(var + 1e-5f);
#pragma unroll
  for (int i = 0; i < 4; i++) {
    int j = t + i * 256;
    out[(size_t)b * 1024 + j] = (y[i] - mu) * inv * gamma[j] + beta[j];
  }
}

// ---------------- host launch ----------------
extern "C" void kernel_launch(void* const* d_in, const int* in_sizes, int n_in,
                              void* d_out, int out_size, void* d_ws, size_t ws_size,
                              hipStream_t stream) {
  const float* x     = (const float*)d_in[0];
  const float* hist  = (const float*)d_in[1];
  const float* Wq    = (const float*)d_in[2];
  const float* bq    = (const float*)d_in[3];
  const float* Wk    = (const float*)d_in[4];
  // bk (d_in[5]) dropped exactly: softmax shift invariance.
  const float* Wv    = (const float*)d_in[6];
  const float* bv    = (const float*)d_in[7];
  const float* Wo    = (const float*)d_in[8];
  const float* bo    = (const float*)d_in[9];
  const float* dil_w = (const float*)d_in[10];
  const float* gamma = (const float*)d_in[11];
  const float* beta  = (const float*)d_in[12];
  char* ws = (char*)d_ws;

  _Float16* WoT   = (_Float16*)(ws + OFF_WOT);
  _Float16* Wv16  = (_Float16*)(ws + OFF_WV16);
  _Float16* Wk16  = (_Float16*)(ws + OFF_WK16);
  _Float16* Wq16  = (_Float16*)(ws + OFF_WQ16);
  _Float16* xb    = (_Float16*)(ws + OFF_XB);
  _Float16* G     = (_Float16*)(ws + OFF_G);
  _Float16* WVOT  = (_Float16*)(ws + OFF_WVOT);
  _Float16* WQKT  = (_Float16*)(ws + OFF_WQKT);
  float* bvwo     = (float*)(ws + OFF_BVWO);
  float* bqk      = (float*)(ws + OFF_BQK);
  _Float16* PHred = (_Float16*)(ws + OFF_PHR);
  float* oppart   = (float*)(ws + OFF_OPP);    // 16 MB (OPP + dead histb head)
  _Float16* histb = (_Float16*)(ws + OFF_HB);
  _Float16* histT = (_Float16*)(ws + OFF_HT);
  _Float16* Eb    = (_Float16*)(ws + OFF_S);
  float* gpart    = (float*)(ws + OFF_S);      // 16 MB; dead before S writes Eb
  float* zframe   = (float*)(ws + OFF_PHR);    // 256 KB in PHR (no chunk overlap)
  float* w4       = (float*)(ws + OFF_G);      // 16 KB; G dead after S

  // 1) prep
  prep_kernel<<<dim3(8448), 256, 0, stream>>>(Wo, Wv, Wk, Wq, x, hist,
                                              WoT, Wv16, Wk16, Wq16, xb, histb, histT);
  // 2) wpack
  wpack_kernel<<<dim3(532), 256, 0, stream>>>(WoT, Wv16, Wk16, Wq16, bv, bq,
                                              WVOT, WQKT, bvwo, bqk);
  // 3) G split-K-4 partials (256 blocks) + reduce
  gemm_g_kernel<<<dim3(8, 2, 16), 256, 0, stream>>>(xb, WQKT, gpart);
  reduce_g_kernel<<<dim3(1024), 256, 0, stream>>>(gpart, bqk, G);
  // 4) E = exp(G @ hist^T) + Zframe
  gemm256_s_kernel<<<dim3(256), 512, 0, stream>>>(G, histb, Eb, zframe);
  // 5) PH class-partials (256x128 tiles, 2 blocks/CU; + csoftmax block 512)
  gemm256_ph_kernel<<<dim3(513), 256, 0, stream>>>(Eb, histT, zframe, dil_w, w4, ws);
  // 6) reduce: class sums x w4 -> PHred
  reduce_ph_kernel<<<dim3(512), 256, 0, stream>>>(ws, w4, PHred);
  // 7) FO split-16 (256 blocks)
  gemm_f16_kernel<true><<<dim3(8, 2, 16), 256, 0, stream>>>(
      PHred, 4096, 256, WVOT, 4096, 256, 8, nullptr, 0, 1.0f / 256.0f,
      (void*)oppart, 1024, 262144);
  // 8) 16-way reduce + bo + bv@Wo + residual + layernorm
  ln_kernel<<<dim3(256), 256, 0, stream>>>(x, oppart, bo, bvwo, gamma, beta, (float*)d_out);
}

// Round 17
// 293.993 us; speedup vs baseline: 1.0817x; 1.0136x over previous
//
#include <hip/hip_runtime.h>

// TemporalDilatedAttention on gfx950 — round 23
// vs R22 (PASSED 298.0us, best): 2-blocks/CU PH was NULL -> the 26-31%
// MfmaUtil plateau is structural across the whole schedule matrix; GEMM
// cores frozen (byte-identical to R22). This round: tail/traffic fixes.
// (1) PH csoftmax block moved bid 512 -> bid 0 (was a serialized TAIL at
//     exactly 2 blk/CU; GEMM uses bid-1, XCD pin survives uniform shift);
// (2) wpack dot blocks moved to bids 0-19 (512 GEMM blocks = exactly 2/CU,
//     no straggler tail);
// (3) FO partials f32 -> f16 (oppart 16->8MB; same precision argument as
//     the f16 PH chunks which held absmax at 0.015625); ln rewritten with
//     contiguous per-thread columns (float4/half4 loads, coalesced).

#define DD    1024
#define TALL  16384

typedef _Float16 half8  __attribute__((ext_vector_type(8)));
typedef _Float16 half4v __attribute__((ext_vector_type(4)));
typedef float    floatx4 __attribute__((ext_vector_type(4)));
typedef unsigned int u32;

// ---------------- workspace layout (bytes), ~132.5 MB ----------------
static const size_t OFF_WOT  = 0;          // 2 MB  Wo^T f16
static const size_t OFF_WV16 = 2097152;    // 2 MB  Wv f16
static const size_t OFF_WK16 = 4194304;    // 2 MB  Wk f16
static const size_t OFF_WQ16 = 6291456;    // 2 MB  Wq f16
static const size_t OFF_XB   = 8388608;    // 0.5 MB x f16
static const size_t OFF_G    = 8912896;    // 2 MB  G f16; w4 table after S
static const size_t OFF_WVOT = 11010048;   // 8 MB  WVOT f16 (LIVE through FO)
static const size_t OFF_WQKT = 19398656;   // 8 MB  WQKT f16 (dead after G; chunks 4-7 here)
static const size_t OFF_BVWO = 27787264;   // 4 KB  bv@Wo f32
static const size_t OFF_BQK  = 27791360;   // 16 KB bqk f32
static const size_t OFF_PHR  = 27807744;   // 2 MB  zframe (S->PH), then PHred f16
static const size_t OFF_OPP  = 29904896;   // 8 MB  FO partials f16 (chunks 8-11 bytes; FO after reduce)
static const size_t OFF_HB   = 38293504;   // 32 MB histb (dead after S)
static const size_t OFF_HT   = 71848960;   // 32 MB hist^T f16 [feat][t]
static const size_t OFF_S    = 105403392;  // 32 MB: G split-K partials (16MB) then E f16

// PH f16 partial chunks: 16 x 2 MB over regions dead during launches 5-6.
__device__ __forceinline__ size_t chunk16_off(int g) {
  if (g < 4)  return (size_t)g * 2097152;
  if (g < 8)  return 19398656 + (size_t)(g - 4) * 2097152;
  if (g < 12) return 29904896 + (size_t)(g - 8) * 2097152;
  return 38293504 + (size_t)(g - 12) * 2097152;
}

// Frame-class chunk map: chunk g, sub-frame j (0..3) -> frame index.
__device__ __forceinline__ int frame_of(int g, int j) {
  if (g < 12) { int m = g * 4 + j; return m + m / 3 + 1; }
  if (g < 14) return 4 + 8 * ((g - 12) * 4 + j);
  if (g == 14) return 8 + 16 * j;
  return 16 * j;
}
__device__ __forceinline__ size_t foff(int g, int t) {
  return (size_t)frame_of(g, t >> 3) * 512 + (size_t)(t & 7) * 64;
}

// ---------------- async global->LDS, 16B per lane ----------------
__device__ __forceinline__ void gl_lds16(const void* g, void* l) {
  __builtin_amdgcn_global_load_lds((const __attribute__((address_space(1))) u32*)g,
                                   (__attribute__((address_space(3))) u32*)l, 16, 0, 0);
}

// ---------------- prep (unchanged) ----------------
__global__ void prep_kernel(const float* __restrict__ Wo, const float* __restrict__ Wv,
                            const float* __restrict__ Wk, const float* __restrict__ Wq,
                            const float* __restrict__ x, const float* __restrict__ hist,
                            _Float16* __restrict__ WoT, _Float16* __restrict__ Wv16,
                            _Float16* __restrict__ Wk16, _Float16* __restrict__ Wq16,
                            _Float16* __restrict__ xb, _Float16* __restrict__ histb,
                            _Float16* __restrict__ histT) {
  int bid = blockIdx.x, tid = threadIdx.x;
  if (bid < 1024) {                        // Wo transpose+cvt
    int k0 = (bid & 31) * 32, n0 = (bid >> 5) * 32;
    __shared__ float t32[32][33];
    int tx = tid & 31, ty = tid >> 5;
#pragma unroll
    for (int i = 0; i < 4; i++) {
      int r = ty + i * 8;
      t32[r][tx] = Wo[(size_t)(k0 + r) * DD + n0 + tx];
    }
    __syncthreads();
#pragma unroll
    for (int i = 0; i < 4; i++) {
      int r = ty + i * 8;
      WoT[(size_t)(n0 + r) * DD + k0 + tx] = (_Float16)t32[tx][r];
    }
  } else if (bid < 4352) {                 // plain cvt
    const float* src; _Float16* dst; size_t i;
    if (bid < 2048)      { src = Wv; dst = Wv16; i = (size_t)(bid - 1024) * 256 + tid; }
    else if (bid < 3072) { src = Wk; dst = Wk16; i = (size_t)(bid - 2048) * 256 + tid; }
    else if (bid < 4096) { src = Wq; dst = Wq16; i = (size_t)(bid - 3072) * 256 + tid; }
    else                 { src = x;  dst = xb;   i = (size_t)(bid - 4096) * 256 + tid; }
    float4 v = ((const float4*)src)[i];
    half4v h = {(_Float16)v.x, (_Float16)v.y, (_Float16)v.z, (_Float16)v.w};
    *(half4v*)(dst + 4 * i) = h;
  } else {                                 // hist dual write
    int tb = bid - 4352;
    int t0 = (tb & 255) * 64, f0 = (tb >> 8) * 64;
    __shared__ _Float16 lt[64][72];
    int r = tid >> 2, c0 = (tid & 3) * 16;
    half8 s0, s1;
#pragma unroll
    for (int i = 0; i < 4; i++) {
      float4 v = *(const float4*)&hist[(size_t)(t0 + r) * 1024 + f0 + c0 + i * 4];
      half4v h = {(_Float16)v.x, (_Float16)v.y, (_Float16)v.z, (_Float16)v.w};
      *(half4v*)&lt[r][c0 + i * 4] = h;
      if (i < 2) { s0[i*4]=h[0]; s0[i*4+1]=h[1]; s0[i*4+2]=h[2]; s0[i*4+3]=h[3]; }
      else { s1[(i-2)*4]=h[0]; s1[(i-2)*4+1]=h[1]; s1[(i-2)*4+2]=h[2]; s1[(i-2)*4+3]=h[3]; }
    }
    *(half8*)&histb[(size_t)(t0 + r) * 1024 + f0 + c0] = s0;
    *(half8*)&histb[(size_t)(t0 + r) * 1024 + f0 + c0 + 8] = s1;
    __syncthreads();
    int fr = tid >> 2, tc0 = (tid & 3) * 16;
    half8 o0, o1;
#pragma unroll
    for (int j = 0; j < 8; j++) { o0[j] = lt[tc0 + j][fr]; o1[j] = lt[tc0 + 8 + j][fr]; }
    *(half8*)&histT[(size_t)(f0 + fr) * TALL + t0 + tc0] = o0;
    *(half8*)&histT[(size_t)(f0 + fr) * TALL + t0 + tc0 + 8] = o1;
  }
}

// ---------------- R9 128x128 core (wpack/G/FO) ----------------------------
__device__ __forceinline__ void gemm_core(const _Float16* __restrict__ A, size_t lda,
                                          const _Float16* __restrict__ B, size_t ldb,
                                          int kIters, _Float16* As, _Float16* Bs,
                                          int tid, floatx4 acc[4][4]) {
  int lane = tid & 63, w = tid >> 6;
  int l15 = lane & 15, quad = lane >> 4;
  int wm = (w >> 1) * 64, wn = (w & 1) * 64;
  int swz = ((tid & 3) ^ ((tid >> 3) & 3)) * 8;
  int pch = (quad ^ ((l15 >> 1) & 3)) * 8;
  const char* gA0 = (const char*)(A + (size_t)(tid >> 2) * lda + swz);
  const char* gA1 = (const char*)(A + ((size_t)(tid >> 2) + 64) * lda + swz);
  const char* gB0 = (const char*)(B + (size_t)(tid >> 2) * ldb + swz);
  const char* gB1 = (const char*)(B + ((size_t)(tid >> 2) + 64) * ldb + swz);
  _Float16* lA = As + w * 512;
  _Float16* lB = Bs + w * 512;
#define GC_STAGE(buf, k)                                    \
  do {                                                      \
    size_t off_ = (size_t)(k) * 64;                         \
    gl_lds16(gA0 + off_, lA + (buf) * 4096);                \
    gl_lds16(gA1 + off_, lA + (buf) * 4096 + 2048);         \
    gl_lds16(gB0 + off_, lB + (buf) * 4096);                \
    gl_lds16(gB1 + off_, lB + (buf) * 4096 + 2048);         \
  } while (0)
#define GC_STEP(buf, k)                                                       \
  do {                                                                        \
    if ((k) + 1 < kIters) asm volatile("s_waitcnt vmcnt(4)" ::: "memory");    \
    else                  asm volatile("s_waitcnt vmcnt(0)" ::: "memory");    \
    asm volatile("s_barrier" ::: "memory");                                   \
    const _Float16* Ac_ = As + (buf) * 4096;                                  \
    const _Float16* Bc_ = Bs + (buf) * 4096;                                  \
    half8 a_[4];                                                              \
    _Pragma("unroll")                                                         \
    for (int mi = 0; mi < 4; mi++)                                            \
      a_[mi] = *(const half8*)&Ac_[(wm + mi * 16 + l15) * 32 + pch];          \
    _Pragma("unroll")                                                         \
    for (int ni = 0; ni < 4; ni++) {                                          \
      half8 b8_ = *(const half8*)&Bc_[(wn + ni * 16 + l15) * 32 + pch];       \
      _Pragma("unroll")                                                       \
      for (int mi = 0; mi < 4; mi++)                                          \
        acc[mi][ni] = __builtin_amdgcn_mfma_f32_16x16x32_f16(a_[mi], b8_,     \
                                                             acc[mi][ni], 0, 0, 0); \
    }                                                                         \
    asm volatile("s_waitcnt lgkmcnt(0)" ::: "memory");                        \
    asm volatile("s_barrier" ::: "memory");                                   \
    if ((k) + 2 < kIters) GC_STAGE(buf, (k) + 2);                             \
  } while (0)
  GC_STAGE(0, 0);
  GC_STAGE(1, 1);
  for (int kk = 0; kk < kIters; kk += 2) {
    GC_STEP(0, kk);
    GC_STEP(1, kk + 1);
  }
#undef GC_STEP
#undef GC_STAGE
}

// ---------------- 256x256 8-wave minimal-barrier core (S) -----------------
template <typename OFF>
__device__ __forceinline__ void gemm256_run(const _Float16* __restrict__ A, size_t lda,
                                            const _Float16* __restrict__ B, size_t ldb,
                                            OFF off, _Float16* As, _Float16* Bs,
                                            int tid, floatx4 acc[8][4]) {
  int lane = tid & 63, w = tid >> 6;
  int l15 = lane & 15, quad = lane >> 4;
  int wr = w >> 2, wc = w & 3;
  int pch = (quad ^ ((l15 >> 1) & 3)) * 8;
  int srow = tid >> 2;
  int schunk = (tid & 3) ^ ((tid >> 3) & 3);
  const char* gA0 = (const char*)(A + (size_t)srow * lda + schunk * 8);
  const char* gA1 = (const char*)(A + (size_t)(srow + 128) * lda + schunk * 8);
  const char* gB0 = (const char*)(B + (size_t)srow * ldb + schunk * 8);
  const char* gB1 = (const char*)(B + (size_t)(srow + 128) * ldb + schunk * 8);
  _Float16* lA = As + w * 512;
  _Float16* lB = Bs + w * 512;
#define PSTA(buf, t)                                          \
  do { size_t o_ = off(t);                                    \
    gl_lds16(gA0 + o_, lA + (buf) * 8192);                    \
    gl_lds16(gA1 + o_, lA + (buf) * 8192 + 4096);             \
  } while (0)
#define PSTB(buf, t)                                          \
  do { size_t o_ = off(t);                                    \
    gl_lds16(gB0 + o_, lB + (buf) * 8192);                    \
    gl_lds16(gB1 + o_, lB + (buf) * 8192 + 4096);             \
  } while (0)
  PSTA(0, 0); PSTB(0, 0);
  PSTA(1, 1); PSTB(1, 1);
  PSTA(2, 2); PSTB(2, 2);
  for (int t = 0; t < 32; ++t) {
    int buf = t & 3;
    if (t + 2 < 32)      asm volatile("s_waitcnt vmcnt(8)" ::: "memory");
    else if (t + 1 < 32) asm volatile("s_waitcnt vmcnt(4)" ::: "memory");
    else                 asm volatile("s_waitcnt vmcnt(0)" ::: "memory");
    asm volatile("s_barrier" ::: "memory");
    const _Float16* Ac = As + buf * 8192;
    const _Float16* Bc = Bs + buf * 8192;
    half8 b8[4], a8[4];
#pragma unroll
    for (int ni = 0; ni < 4; ni++)
      b8[ni] = *(const half8*)&Bc[(wc * 64 + ni * 16 + l15) * 32 + pch];
#pragma unroll
    for (int mi = 0; mi < 4; mi++)
      a8[mi] = *(const half8*)&Ac[(wr * 128 + mi * 16 + l15) * 32 + pch];
    if (t + 3 < 32) PSTA((t + 3) & 3, t + 3);
    asm volatile("s_waitcnt lgkmcnt(0)" ::: "memory");
    __builtin_amdgcn_s_setprio(1);
#pragma unroll
    for (int mi = 0; mi < 4; mi++)
#pragma unroll
      for (int ni = 0; ni < 4; ni++)
        acc[mi][ni] = __builtin_amdgcn_mfma_f32_16x16x32_f16(a8[mi], b8[ni], acc[mi][ni], 0, 0, 0);
    __builtin_amdgcn_s_setprio(0);
#pragma unroll
    for (int mi = 0; mi < 4; mi++)
      a8[mi] = *(const half8*)&Ac[(wr * 128 + 64 + mi * 16 + l15) * 32 + pch];
    if (t + 3 < 32) PSTB((t + 3) & 3, t + 3);
    asm volatile("s_waitcnt lgkmcnt(0)" ::: "memory");
    __builtin_amdgcn_s_setprio(1);
#pragma unroll
    for (int mi = 0; mi < 4; mi++)
#pragma unroll
      for (int ni = 0; ni < 4; ni++)
        acc[4 + mi][ni] = __builtin_amdgcn_mfma_f32_16x16x32_f16(a8[mi], b8[ni], acc[4 + mi][ni], 0, 0, 0);
    __builtin_amdgcn_s_setprio(0);
  }
#undef PSTA
#undef PSTB
}

struct LinOff { __device__ __forceinline__ size_t operator()(int t) const { return (size_t)t * 64; } };
struct ClsOff { int g; __device__ __forceinline__ size_t operator()(int t) const { return foff(g, t); } };

// ---------------- generic single-B GEMM (R9 core) ----------------
template <bool OUTF32>
__launch_bounds__(256, 3)
__global__ void gemm_f16_kernel(const _Float16* __restrict__ A, size_t lda, size_t aoffz,
                                const _Float16* __restrict__ B, size_t ldb, size_t boffz,
                                int kIters, const float* __restrict__ bias, size_t biasoffz,
                                float scale, void* __restrict__ C, size_t ldc, size_t coffz) {
  __shared__ __align__(16) _Float16 As[8192];
  __shared__ __align__(16) _Float16 Bs[8192];
  int tid = threadIdx.x;
  const _Float16* Ab = A + aoffz * blockIdx.z + (size_t)(blockIdx.y * 128) * lda;
  const _Float16* Bb = B + boffz * blockIdx.z + (size_t)(blockIdx.x * 128) * ldb;
  floatx4 acc[4][4];
  floatx4 zero = {0.f, 0.f, 0.f, 0.f};
#pragma unroll
  for (int a = 0; a < 4; a++)
#pragma unroll
    for (int b = 0; b < 4; b++) acc[a][b] = zero;
  gemm_core(Ab, lda, Bb, ldb, kIters, As, Bs, tid, acc);
  int lane = tid & 63, w = tid >> 6;
  int l15 = lane & 15, quad = lane >> 4;
  int wm = (w >> 1) * 64, wn = (w & 1) * 64;
#pragma unroll
  for (int mi = 0; mi < 4; mi++)
#pragma unroll
    for (int ni = 0; ni < 4; ni++) {
      int colg = blockIdx.x * 128 + wn + ni * 16 + l15;
      float bv = bias ? bias[biasoffz * blockIdx.z + colg] : 0.f;
#pragma unroll
      for (int r = 0; r < 4; r++) {
        int rowg = blockIdx.y * 128 + wm + mi * 16 + quad * 4 + r;
        float v = (acc[mi][ni][r] + bv) * scale;
        size_t idx = coffz * blockIdx.z + (size_t)rowg * ldc + colg;
        if (OUTF32) ((float*)C)[idx] = v;
        else ((_Float16*)C)[idx] = (_Float16)v;
      }
    }
}

// ---------------- G gemm, split-K-4: z = sp*4 + h, 256 blocks -------------
__launch_bounds__(256, 3)
__global__ void gemm_g_kernel(const _Float16* __restrict__ xb, const _Float16* __restrict__ WQKT,
                              float* __restrict__ gpart) {
  __shared__ __align__(16) _Float16 As[8192];
  __shared__ __align__(16) _Float16 Bs[8192];
  int tid = threadIdx.x;
  int z = blockIdx.z, sp = z >> 2, h = z & 3;
  const _Float16* Ab = xb + sp * 256 + (size_t)(blockIdx.y * 128) * 1024;
  const _Float16* Bb = WQKT + (size_t)h * 1048576 + sp * 256 + (size_t)(blockIdx.x * 128) * 1024;
  floatx4 acc[4][4];
  floatx4 zero = {0.f, 0.f, 0.f, 0.f};
#pragma unroll
  for (int a = 0; a < 4; a++)
#pragma unroll
    for (int b = 0; b < 4; b++) acc[a][b] = zero;
  gemm_core(Ab, 1024, Bb, 1024, 8, As, Bs, tid, acc);
  int lane = tid & 63, w = tid >> 6;
  int l15 = lane & 15, quad = lane >> 4;
  int wm = (w >> 1) * 64, wn = (w & 1) * 64;
#pragma unroll
  for (int mi = 0; mi < 4; mi++)
#pragma unroll
    for (int ni = 0; ni < 4; ni++) {
      int col = blockIdx.x * 128 + wn + ni * 16 + l15;
#pragma unroll
      for (int r = 0; r < 4; r++) {
        int row = blockIdx.y * 128 + wm + mi * 16 + quad * 4 + r;
        gpart[(size_t)z * 262144 + (size_t)row * 1024 + col] = acc[mi][ni][r];
      }
    }
}

// ---------------- reduce_g: 4 sp-partials + bqk -> G f16 ------------------
__global__ void reduce_g_kernel(const float* __restrict__ gpart, const float* __restrict__ bqk,
                                _Float16* __restrict__ G) {
  size_t e4 = ((size_t)blockIdx.x * 256 + threadIdx.x) * 4;   // 1024 blocks
  int h = (int)(e4 >> 18);
  size_t rem = e4 & 262143;
  int d = (int)(e4 & 1023);
  float4 s = *(const float4*)&bqk[h * 1024 + d];
#pragma unroll
  for (int sp = 0; sp < 4; sp++) {
    float4 p = *(const float4*)&gpart[(size_t)(sp * 4 + h) * 262144 + rem];
    s.x += p.x; s.y += p.y; s.z += p.z; s.w += p.w;
  }
  half4v o = {(_Float16)s.x, (_Float16)s.y, (_Float16)s.z, (_Float16)s.w};
  *(half4v*)&G[e4] = o;
}

// ---------------- wpack: dots first (bids 0-19), 512 GEMM blocks ----------
__launch_bounds__(256, 3)
__global__ void wpack_kernel(const _Float16* __restrict__ WoT, const _Float16* __restrict__ Wv16,
                             const _Float16* __restrict__ Wk16, const _Float16* __restrict__ Wq16,
                             const float* __restrict__ bv, const float* __restrict__ bq,
                             _Float16* __restrict__ WVOT, _Float16* __restrict__ WQKT,
                             float* __restrict__ bvwo, float* __restrict__ bqk) {
  __shared__ __align__(16) _Float16 As[8192];
  __shared__ __align__(16) _Float16 Bs[8192];
  int bid = blockIdx.x, tid = threadIdx.x;
  if (bid < 4) {                            // bvwo dots
    int j = bid * 256 + tid;
    const half8* row = (const half8*)(WoT + (size_t)j * 1024);
    float a = 0.f;
    for (int c = 0; c < 128; c++) {
      half8 w8 = row[c];
#pragma unroll
      for (int e = 0; e < 8; e++) a += bv[c * 8 + e] * (float)w8[e];
    }
    bvwo[j] = a;
  } else if (bid < 20) {                    // bqk dots
    int idx = (bid - 4) * 256 + tid;
    int h = idx >> 10, f = idx & 1023;
    const _Float16* row = Wk16 + (size_t)f * 1024 + h * 256;
    float a = 0.f;
    for (int n = 0; n < 256; n++) a += bq[h * 256 + n] * (float)row[n];
    bqk[idx] = a * 0.0625f;
  } else {                                  // 512 GEMM blocks (2/CU exactly)
    int gb = bid - 20;
    bool isQK = gb >= 256;
    int g = gb & 255;
    int x = g & 7, y = (g >> 3) & 7, z = g >> 6;
    const _Float16* A = isQK ? Wk16 : WoT;
    const _Float16* B = isQK ? Wq16 : Wv16;
    const _Float16* Ab = A + 256 * z + (size_t)(y * 128) * 1024;
    const _Float16* Bb = B + 256 * z + (size_t)(x * 128) * 1024;
    floatx4 acc[4][4];
    floatx4 zero = {0.f, 0.f, 0.f, 0.f};
#pragma unroll
    for (int a = 0; a < 4; a++)
#pragma unroll
      for (int b = 0; b < 4; b++) acc[a][b] = zero;
    gemm_core(Ab, 1024, Bb, 1024, 8, As, Bs, tid, acc);
    float scale = isQK ? 0.0625f : 1.0f;
    _Float16* C = isQK ? WQKT : WVOT;
    size_t ldc = isQK ? 1024 : 4096;
    size_t zoff = isQK ? (size_t)1048576 * z : (size_t)1024 * z;
    int lane = tid & 63, w = tid >> 6;
    int l15 = lane & 15, quad = lane >> 4;
    int wm = (w >> 1) * 64, wn = (w & 1) * 64;
#pragma unroll
    for (int mi = 0; mi < 4; mi++)
#pragma unroll
      for (int ni = 0; ni < 4; ni++) {
        int col = x * 128 + wn + ni * 16 + l15;
#pragma unroll
        for (int r = 0; r < 4; r++) {
          int row = y * 128 + wm + mi * 16 + quad * 4 + r;
          C[zoff + (size_t)row * ldc + col] = (_Float16)(acc[mi][ni][r] * scale);
        }
      }
  }
}

// ---------------- S gemm: minimal-barrier core + exp epilogue + Zframe ----
__launch_bounds__(512, 2)
__global__ void gemm256_s_kernel(const _Float16* __restrict__ G, const _Float16* __restrict__ histb,
                                 _Float16* __restrict__ Eout, float* __restrict__ zframe) {
  __shared__ __align__(16) _Float16 SM[65536];
  _Float16* As = SM;
  _Float16* Bs = SM + 32768;
  int bid = blockIdx.x, tid = threadIdx.x;
  int h = bid >> 6, nt = bid & 63;
  const _Float16* Ab = G + (size_t)h * 262144;
  const _Float16* Bb = histb + (size_t)(nt * 256) * 1024;
  floatx4 acc[8][4];
  floatx4 zero = {0.f, 0.f, 0.f, 0.f};
#pragma unroll
  for (int a = 0; a < 8; a++)
#pragma unroll
    for (int b = 0; b < 4; b++) acc[a][b] = zero;
  gemm256_run(Ab, 1024, Bb, 1024, LinOff{}, As, Bs, tid, acc);
  int lane = tid & 63, w = tid >> 6;
  int l15 = lane & 15, quad = lane >> 4;
  int wr = w >> 2, wc = w & 3;
  __syncthreads();
#pragma unroll
  for (int mh = 0; mh < 2; mh++)
#pragma unroll
    for (int mi = 0; mi < 4; mi++)
#pragma unroll
      for (int ni = 0; ni < 4; ni++) {
        int col = wc * 64 + ni * 16 + l15;
#pragma unroll
        for (int r = 0; r < 4; r++) {
          int row = wr * 128 + mh * 64 + mi * 16 + quad * 4 + r;
          int colsw = col ^ (((row >> 2) & 3) << 3);
          SM[row * 256 + colsw] = (_Float16)__expf(acc[mh * 4 + mi][ni][r]);
        }
      }
  __syncthreads();
  int c32 = lane & 31, hs = lane >> 5;
#pragma unroll
  for (int it = 0; it < 16; it++) {
    int row = w * 32 + it * 2 + hs;
    int cs = (c32 * 8) ^ (((row >> 2) & 3) << 3);
    half8 v = *(const half8*)&SM[row * 256 + cs];
    float s = 0.f;
#pragma unroll
    for (int j = 0; j < 8; j++) s += (float)v[j];
#pragma unroll
    for (int off = 1; off <= 16; off <<= 1) s += __shfl_xor(s, off, 64);
    *(half8*)&Eout[(size_t)h * 4194304 + (size_t)row * TALL + nt * 256 + c32 * 8] = v;
    if (c32 == 0) zframe[(size_t)(h * 256 + row) * 64 + nt] = s;
  }
}

// ---------------- PH gemm: csoftmax FIRST (bid 0), GEMM bids 1-512 --------
__launch_bounds__(256, 2)
__global__ void gemm256_ph_kernel(const _Float16* __restrict__ E, const _Float16* __restrict__ histT,
                                  const float* __restrict__ zframe, const float* __restrict__ dil_w,
                                  float* __restrict__ w4, char* __restrict__ ws) {
  __shared__ __align__(16) _Float16 SM[32768];   // 64 KB
  int bid = blockIdx.x, tid = threadIdx.x;
  if (bid == 0) {                          // csoftmax: zframe -> w4 (no tail)
    float w0 = dil_w[0], w1 = dil_w[1], w2 = dil_w[2], w3 = dil_w[3];
    float wmx = fmaxf(fmaxf(w0, w1), fmaxf(w2, w3));
    float e0 = __expf(w0 - wmx), e1 = __expf(w1 - wmx), e2 = __expf(w2 - wmx), e3 = __expf(w3 - wmx);
    float wsum = e0 + e1 + e2 + e3;
#pragma unroll
    for (int i = 0; i < 4; i++) {
      int row = i * 256 + tid;
      const float* z = zframe + (size_t)row * 64;
      float z1 = 0.f, z4 = 0.f, z8 = 0.f, z16 = 0.f;
#pragma unroll
      for (int f = 0; f < 64; f++) {
        float v = z[f];
        z1 += v;
        if (!(f & 3))  z4 += v;
        if (!(f & 7))  z8 += v;
        if (!(f & 15)) z16 += v;
      }
      float b0 = (e0 / wsum) / z1 * 256.0f;
      float b1 = (e1 / wsum) / z4 * 256.0f;
      float b2 = (e2 / wsum) / z8 * 256.0f;
      float b3 = (e3 / wsum) / z16 * 256.0f;
      float* wr = w4 + (size_t)row * 4;
      wr[0] = b0;
      wr[1] = b0 + b1;
      wr[2] = b0 + b1 + b2;
      wr[3] = b0 + b1 + b2 + b3;
    }
    return;
  }
  _Float16* As = SM;            // 2 bufs x 8192 f16 (256x32)
  _Float16* Bs = SM + 16384;    // 2 bufs x 4096 f16 (128x32)
  int b1i = bid - 1;                       // 0..511; uniform shift keeps XCD grouping
  int xcd = b1i & 7, slot = b1i >> 3;
  int g = xcd + 8 * (slot >> 5);
  int member = slot & 31;
  int h = member >> 3, nt = member & 7;
  int lane = tid & 63, w = tid >> 6;
  int l15 = lane & 15, quad = lane >> 4;
  int wr = w >> 1, wc = w & 1;             // wave grid 2 (M) x 2 (N)
  int pch = (quad ^ ((l15 >> 1) & 3)) * 8;
  int srow = tid >> 2;                      // 0..63
  int schunk = (tid & 3) ^ ((tid >> 3) & 3);
  const _Float16* A = E + (size_t)h * 4194304;
  const _Float16* B = histT + (size_t)(nt * 128) * TALL;
  const char* gA0 = (const char*)(A + (size_t)srow * TALL + schunk * 8);
  const char* gA1 = (const char*)(A + (size_t)(srow + 64) * TALL + schunk * 8);
  const char* gA2 = (const char*)(A + (size_t)(srow + 128) * TALL + schunk * 8);
  const char* gA3 = (const char*)(A + (size_t)(srow + 192) * TALL + schunk * 8);
  const char* gB0 = (const char*)(B + (size_t)srow * TALL + schunk * 8);
  const char* gB1 = (const char*)(B + (size_t)(srow + 64) * TALL + schunk * 8);
  _Float16* lA = As + w * 512;
  _Float16* lB = Bs + w * 512;
  floatx4 acc[8][4];
  floatx4 zero = {0.f, 0.f, 0.f, 0.f};
#pragma unroll
  for (int a = 0; a < 8; a++)
#pragma unroll
    for (int b = 0; b < 4; b++) acc[a][b] = zero;
#define HST(buf, t)                                           \
  do { size_t o_ = foff(g, t);                                \
    gl_lds16(gA0 + o_, lA + (buf) * 8192);                    \
    gl_lds16(gA1 + o_, lA + (buf) * 8192 + 2048);             \
    gl_lds16(gA2 + o_, lA + (buf) * 8192 + 4096);             \
    gl_lds16(gA3 + o_, lA + (buf) * 8192 + 6144);             \
    gl_lds16(gB0 + o_, lB + (buf) * 4096);                    \
    gl_lds16(gB1 + o_, lB + (buf) * 4096 + 2048);             \
  } while (0)
  HST(0, 0);
  HST(1, 1);
  for (int t = 0; t < 32; ++t) {
    int buf = t & 1;
    if (t + 1 < 32) asm volatile("s_waitcnt vmcnt(6)" ::: "memory");
    else            asm volatile("s_waitcnt vmcnt(0)" ::: "memory");
    asm volatile("s_barrier" ::: "memory");
    const _Float16* Ac = As + buf * 8192;
    const _Float16* Bc = Bs + buf * 4096;
    half8 b8[4], a8[8];
#pragma unroll
    for (int ni = 0; ni < 4; ni++)
      b8[ni] = *(const half8*)&Bc[(wc * 64 + ni * 16 + l15) * 32 + pch];
#pragma unroll
    for (int mi = 0; mi < 8; mi++)
      a8[mi] = *(const half8*)&Ac[(wr * 128 + mi * 16 + l15) * 32 + pch];
    asm volatile("s_waitcnt lgkmcnt(0)" ::: "memory");
    __builtin_amdgcn_s_setprio(1);
#pragma unroll
    for (int mi = 0; mi < 8; mi++)
#pragma unroll
      for (int ni = 0; ni < 4; ni++)
        acc[mi][ni] = __builtin_amdgcn_mfma_f32_16x16x32_f16(a8[mi], b8[ni], acc[mi][ni], 0, 0, 0);
    __builtin_amdgcn_s_setprio(0);
    asm volatile("s_barrier" ::: "memory");
    if (t + 2 < 32) HST(buf, t + 2);
  }
#undef HST
  // ---- epilogue: swizzled LDS transpose (256x128), logical-col stores ----
  __syncthreads();
#pragma unroll
  for (int mi = 0; mi < 8; mi++)
#pragma unroll
    for (int ni = 0; ni < 4; ni++) {
      int col = wc * 64 + ni * 16 + l15;
#pragma unroll
      for (int r = 0; r < 4; r++) {
        int row = wr * 128 + mi * 16 + quad * 4 + r;
        int colsw = col ^ (((row >> 2) & 3) << 3);
        SM[row * 128 + colsw] = (_Float16)acc[mi][ni][r];
      }
    }
  __syncthreads();
  _Float16* chunk = (_Float16*)(ws + chunk16_off(g));
  int c16 = lane & 15, rq = lane >> 4;
  int colbase = h * 1024 + nt * 128;
#pragma unroll
  for (int it = 0; it < 16; it++) {
    int row = w * 64 + it * 4 + rq;
    int cs = (c16 * 8) ^ (((row >> 2) & 3) << 3);   // physical LDS position
    half8 v = *(const half8*)&SM[row * 128 + cs];   // logical cols [c16*8, +8)
    *(half8*)&chunk[(size_t)row * 4096 + colbase + c16 * 8] = v;
  }
}

// ---------------- reduce: 4 class sums x per-(h,q) weights -> PHred -------
__global__ void reduce_ph_kernel(const char* __restrict__ ws, const float* __restrict__ w4,
                                 _Float16* __restrict__ PHred) {
  size_t e8 = ((size_t)blockIdx.x * 256 + threadIdx.x) * 8;
  int q = (int)(e8 >> 12);
  int h = (int)((e8 >> 10) & 3);
  const float* wr = w4 + (size_t)(h * 256 + q) * 4;
  float sA[8] = {0,0,0,0,0,0,0,0}, sB[8] = {0,0,0,0,0,0,0,0};
  float sC[8] = {0,0,0,0,0,0,0,0}, sD[8] = {0,0,0,0,0,0,0,0};
#pragma unroll
  for (int g = 0; g < 12; g++) {
    const _Float16* p = (const _Float16*)(ws + chunk16_off(g));
    half8 v = *(const half8*)&p[e8];
#pragma unroll
    for (int j = 0; j < 8; j++) sA[j] += (float)v[j];
  }
#pragma unroll
  for (int g = 12; g < 14; g++) {
    const _Float16* p = (const _Float16*)(ws + chunk16_off(g));
    half8 v = *(const half8*)&p[e8];
#pragma unroll
    for (int j = 0; j < 8; j++) sB[j] += (float)v[j];
  }
  {
    const _Float16* p = (const _Float16*)(ws + chunk16_off(14));
    half8 v = *(const half8*)&p[e8];
#pragma unroll
    for (int j = 0; j < 8; j++) sC[j] += (float)v[j];
  }
  {
    const _Float16* p = (const _Float16*)(ws + chunk16_off(15));
    half8 v = *(const half8*)&p[e8];
#pragma unroll
    for (int j = 0; j < 8; j++) sD[j] += (float)v[j];
  }
  float wA = wr[0], wB = wr[1], wC = wr[2], wD = wr[3];
  half8 o;
#pragma unroll
  for (int j = 0; j < 8; j++)
    o[j] = (_Float16)(wA * sA[j] + wB * sB[j] + wC * sC[j] + wD * sD[j]);
  *(half8*)&PHred[e8] = o;
}

// ---------------- FO 16-way f16-partial reduce + residual + layernorm -----
// Each thread owns 4 CONTIGUOUS cols j = 4*t (float4/half4 loads, coalesced).
__global__ void ln_kernel(const float* __restrict__ x, const _Float16* __restrict__ part2,
                          const float* __restrict__ bo, const float* __restrict__ bvwo,
                          const float* __restrict__ gamma, const float* __restrict__ beta,
                          float* __restrict__ out) {
  int b = blockIdx.x, t = threadIdx.x;
  __shared__ float red[8];
  int j0 = t * 4;
  float4 xv = *(const float4*)&x[(size_t)b * 1024 + j0];
  float4 bov = *(const float4*)&bo[j0];
  float4 bw = *(const float4*)&bvwo[j0];
  float y[4] = {xv.x + bov.x + bw.x, xv.y + bov.y + bw.y,
                xv.z + bov.z + bw.z, xv.w + bov.w + bw.w};
#pragma unroll
  for (int z = 0; z < 16; z++) {
    half4v p = *(const half4v*)&part2[(size_t)z * 262144 + (size_t)b * 1024 + j0];
#pragma unroll
    for (int k = 0; k < 4; k++) y[k] += (float)p[k];
  }
  float sum = y[0] + y[1] + y[2] + y[3];
  float sq = y[0]*y[0] + y[1]*y[1] + y[2]*y[2] + y[3]*y[3];
#pragma unroll
  for (int off = 1; off < 64; off <<= 1) {
    sum += __shfl_xor(sum, off, 64);
    sq += __shfl_xor(sq, off, 64);
  }
  int w = t >> 6, lane = t & 63;
  if (lane == 0) { red[w] = sum; red[4 + w] = sq; }
  __syncthreads();
  sum = red[0] + red[1] + red[2] + red[3];
  sq = red[4] + red[5] + red[6] + red[7];
  float mu = sum * (1.f / 1024.f);
  float var = sq * (1.f / 1024.f) - mu * mu;
  float inv = rsqrtf(var + 1e-5f);
  float4 gv = *(const float4*)&gamma[j0];
  float4 btv = *(const float4*)&beta[j0];
  float4 o;
  o.x = (y[0] - mu) * inv * gv.x + btv.x;
  o.y = (y[1] - mu) * inv * gv.y + btv.y;
  o.z = (y[2] - mu) * inv * gv.z + btv.z;
  o.w = (y[3] - mu) * inv * gv.w + btv.w;
  *(float4*)&out[(size_t)b * 1024 + j0] = o;
}

// ---------------- host launch ----------------
extern "C" void kernel_launch(void* const* d_in, const int* in_sizes, int n_in,
                              void* d_out, int out_size, void* d_ws, size_t ws_size,
                              hipStream_t stream) {
  const float* x     = (const float*)d_in[0];
  const float* hist  = (const float*)d_in[1];
  const float* Wq    = (const float*)d_in[2];
  const float* bq    = (const float*)d_in[3];
  const float* Wk    = (const float*)d_in[4];
  // bk (d_in[5]) dropped exactly: softmax shift invariance.
  const float* Wv    = (const float*)d_in[6];
  const float* bv    = (const float*)d_in[7];
  const float* Wo    = (const float*)d_in[8];
  const float* bo    = (const float*)d_in[9];
  const float* dil_w = (const float*)d_in[10];
  const float* gamma = (const float*)d_in[11];
  const float* beta  = (const float*)d_in[12];
  char* ws = (char*)d_ws;

  _Float16* WoT   = (_Float16*)(ws + OFF_WOT);
  _Float16* Wv16  = (_Float16*)(ws + OFF_WV16);
  _Float16* Wk16  = (_Float16*)(ws + OFF_WK16);
  _Float16* Wq16  = (_Float16*)(ws + OFF_WQ16);
  _Float16* xb    = (_Float16*)(ws + OFF_XB);
  _Float16* G     = (_Float16*)(ws + OFF_G);
  _Float16* WVOT  = (_Float16*)(ws + OFF_WVOT);
  _Float16* WQKT  = (_Float16*)(ws + OFF_WQKT);
  float* bvwo     = (float*)(ws + OFF_BVWO);
  float* bqk      = (float*)(ws + OFF_BQK);
  _Float16* PHred = (_Float16*)(ws + OFF_PHR);
  _Float16* oppart= (_Float16*)(ws + OFF_OPP);  // 8 MB f16 (chunks 8-11 bytes; FO after reduce)
  _Float16* histb = (_Float16*)(ws + OFF_HB);
  _Float16* histT = (_Float16*)(ws + OFF_HT);
  _Float16* Eb    = (_Float16*)(ws + OFF_S);
  float* gpart    = (float*)(ws + OFF_S);       // 16 MB; dead before S writes Eb
  float* zframe   = (float*)(ws + OFF_PHR);     // 256 KB in PHR (no chunk overlap)
  float* w4       = (float*)(ws + OFF_G);       // 16 KB; G dead after S

  // 1) prep
  prep_kernel<<<dim3(8448), 256, 0, stream>>>(Wo, Wv, Wk, Wq, x, hist,
                                              WoT, Wv16, Wk16, Wq16, xb, histb, histT);
  // 2) wpack (dots first, 512 GEMM blocks = 2/CU exactly)
  wpack_kernel<<<dim3(532), 256, 0, stream>>>(WoT, Wv16, Wk16, Wq16, bv, bq,
                                              WVOT, WQKT, bvwo, bqk);
  // 3) G split-K-4 partials (256 blocks) + reduce
  gemm_g_kernel<<<dim3(8, 2, 16), 256, 0, stream>>>(xb, WQKT, gpart);
  reduce_g_kernel<<<dim3(1024), 256, 0, stream>>>(gpart, bqk, G);
  // 4) E = exp(G @ hist^T) + Zframe
  gemm256_s_kernel<<<dim3(256), 512, 0, stream>>>(G, histb, Eb, zframe);
  // 5) PH class-partials (csoftmax = bid 0, GEMM bids 1-512)
  gemm256_ph_kernel<<<dim3(513), 256, 0, stream>>>(Eb, histT, zframe, dil_w, w4, ws);
  // 6) reduce: class sums x w4 -> PHred
  reduce_ph_kernel<<<dim3(512), 256, 0, stream>>>(ws, w4, PHred);
  // 7) FO split-16 (256 blocks, f16 partials)
  gemm_f16_kernel<false><<<dim3(8, 2, 16), 256, 0, stream>>>(
      PHred, 4096, 256, WVOT, 4096, 256, 8, nullptr, 0, 1.0f / 256.0f,
      (void*)oppart, 1024, 262144);
  // 8) 16-way f16 reduce + bo + bv@Wo + residual + layernorm
  ln_kernel<<<dim3(256), 256, 0, stream>>>(x, oppart, bo, bvwo, gamma, beta, (float*)d_out);
}